// Round 11
// baseline (1120.974 us; speedup 1.0000x reference)
//
#include <hip/hip_runtime.h>
#include <math.h>

#define N_ATOMS 100000
#define N_EDGES 1600000
#define NSTRUCT 64
#define APB 64           // atoms per bucket
#define NBUCK 1563       // ceil(N_ATOMS/APB)
#define EPB 8192         // edges per block in bucket passes
#define SEGSTRIDE 89     // 88 used + 1 pad (odd -> all 32 banks)

__device__ __forceinline__ float frcp(float x) { return __builtin_amdgcn_rcpf(x); }
__device__ __forceinline__ float silu(float v) { return v * frcp(1.f + __expf(-v)); }

// ---------------- pack atom data: {m,p},{p,mn,sp},{mhat,1/mn} (48B) ----------------

__global__ void k_pack(const float* __restrict__ pos, const float* __restrict__ mmv,
                       const int* __restrict__ species, float* __restrict__ packed) {
    int a = blockIdx.x * 256 + threadIdx.x;
    if (a >= N_ATOMS) return;
    float mx = mmv[a * 3 + 0], my = mmv[a * 3 + 1], mz = mmv[a * 3 + 2];
    float px = pos[a * 3 + 0], py = pos[a * 3 + 1], pz = pos[a * 3 + 2];
    float mn = sqrtf(mx * mx + my * my + mz * mz + 1e-9f);
    float inv = frcp(mn);
    float4* o = (float4*)packed;
    o[a * 3 + 0] = make_float4(mx, my, mz, px);
    o[a * 3 + 1] = make_float4(py, pz, mn, (float)species[a]);
    o[a * 3 + 2] = make_float4(mx * inv, my * inv, mz * inv, inv);
}

// ---------------- prep: fold emb @ W-layer1 (+bias) per (species/head) ----------------

__global__ void k_prep(const float* __restrict__ embt,
                       const float* __restrict__ Wm1, const float* __restrict__ bm1,
                       const float* __restrict__ Ws1, const float* __restrict__ bs1,
                       float* __restrict__ c1m, float* __restrict__ c1s) {
    int tid = blockIdx.x * 256 + threadIdx.x;
    if (tid < 1152) {
        int h = tid >> 7;
        int sp = (tid >> 5) & 3;
        int o = tid & 31;
        float c = bm1[h * 32 + o];
#pragma unroll
        for (int q = 0; q < 16; q++)
            c = fmaf(embt[sp * 16 + q], Wm1[(h * 24 + 8 + q) * 32 + o], c);
        c1m[tid] = c;
    } else if (tid < 1152 + 256) {
        int k = tid - 1152;
        int sp = k >> 6, o = k & 63;
        float c = bs1[o];
#pragma unroll
        for (int q = 0; q < 16; q++)
            c = fmaf(embt[sp * 16 + q], Ws1[(16 + q) * 64 + o], c);
        c1s[k] = c;
    }
}

// ---------------- bucket histogram ----------------

__global__ __launch_bounds__(1024) void k_bhist(const int* __restrict__ i_idx,
                                                int* __restrict__ bucket_count) {
    __shared__ int h[NBUCK];
    int t = threadIdx.x;
    for (int k = t; k < NBUCK; k += 1024) h[k] = 0;
    __syncthreads();
    int base = blockIdx.x * EPB;
    for (int k = t; k < EPB; k += 1024) {
        int e = base + k;
        if (e < N_EDGES) atomicAdd(&h[i_idx[e] >> 6], 1);
    }
    __syncthreads();
    for (int k = t; k < NBUCK; k += 1024)
        if (h[k]) atomicAdd(&bucket_count[k], h[k]);
}

// ---------------- scan bucket counts (2 elems/thread) ----------------

__global__ __launch_bounds__(1024) void k_bscan(const int* __restrict__ bucket_count,
                                                int* __restrict__ bucket_start,
                                                int* __restrict__ bucket_cursor) {
    __shared__ int sd[2048];
    int t = threadIdx.x;
    int i0 = t, i1 = t + 1024;
    int a0 = (i0 < NBUCK) ? bucket_count[i0] : 0;
    int a1 = (i1 < NBUCK) ? bucket_count[i1] : 0;
    sd[i0] = a0; sd[i1] = a1;
    __syncthreads();
    for (int off = 1; off < 2048; off <<= 1) {
        int v0 = (i0 >= off) ? sd[i0 - off] : 0;
        int v1 = (i1 >= off) ? sd[i1 - off] : 0;
        __syncthreads();
        sd[i0] += v0; sd[i1] += v1;
        __syncthreads();
    }
    if (i0 < NBUCK) { int ex = sd[i0] - a0; bucket_start[i0] = ex; bucket_cursor[i0] = ex; }
    if (i1 < NBUCK) { int ex = sd[i1] - a1; bucket_start[i1] = ex; bucket_cursor[i1] = ex; }
}

// ---------------- scatter packed (il<<17)|j into bucket-major order ----------------

__global__ __launch_bounds__(1024) void k_bscatter(const int* __restrict__ i_idx,
                                                   const int* __restrict__ j_idx,
                                                   int* __restrict__ bucket_cursor,
                                                   unsigned* __restrict__ vb) {
    __shared__ int h[NBUCK];
    __shared__ int gbase[NBUCK];
    int t = threadIdx.x;
    for (int k = t; k < NBUCK; k += 1024) h[k] = 0;
    __syncthreads();
    int base = blockIdx.x * EPB;
    for (int k = t; k < EPB; k += 1024) {
        int e = base + k;
        if (e < N_EDGES) atomicAdd(&h[i_idx[e] >> 6], 1);
    }
    __syncthreads();
    for (int k = t; k < NBUCK; k += 1024) {
        int c = h[k];
        gbase[k] = c ? atomicAdd(&bucket_cursor[k], c) : 0;
        h[k] = 0;   // reuse as local cursor
    }
    __syncthreads();
    for (int k = t; k < EPB; k += 1024) {
        int e = base + k;
        if (e < N_EDGES) {
            int i = i_idx[e];
            int b = i >> 6;
            int r = atomicAdd(&h[b], 1);
            vb[gbase[b] + r] = ((unsigned)(i & 63) << 17) | (unsigned)j_idx[e];
        }
    }
}

// ---------------- fused edge compute + LDS-atomic reduce: one block per bucket ----------------

__global__ __launch_bounds__(512) void k_fused(
    const int* __restrict__ bucket_start, const int* __restrict__ bucket_count,
    const unsigned* __restrict__ vb,
    const float* __restrict__ packed, const float* __restrict__ cheb,
    float* __restrict__ segbuf) {
    __shared__ float segacc[APB * SEGSTRIDE];  // 22.8 KB
    __shared__ float chl[16 * 100];            // 6.4 KB, stride-100 (16B aligned, bank-spread)
    int b = blockIdx.x, t = threadIdx.x;
    int estart = bucket_start[b], nb = bucket_count[b];
    int abase = b * APB;

    for (int k = t; k < APB * SEGSTRIDE; k += 512) segacc[k] = 0.f;
    for (int k = t; k < 1536; k += 512) {
        int pr = k / 96, rm = k - pr * 96;
        chl[pr * 100 + rm] = cheb[k];
    }
    __syncthreads();

    const float4* pk4 = (const float4*)packed;
    for (int k = t; k < nb; k += 512) {
        unsigned v = vb[estart + k];
        int il = (int)(v >> 17);
        int j  = (int)(v & 0x1FFFFu);
        int ia = abase + il;
        float4 i0 = pk4[ia * 3 + 0], i1 = pk4[ia * 3 + 1], i2 = pk4[ia * 3 + 2];
        float4 j0 = pk4[j * 3 + 0],  j1 = pk4[j * 3 + 1],  j2 = pk4[j * 3 + 2];

        float mix = i0.x, miy = i0.y, miz = i0.z;
        float rx = j0.w - i0.w, ry = j1.x - i1.x, rz = j1.y - i1.y;
        int spi = (int)i1.w;
        float mhix = i2.x, mhiy = i2.y, mhiz = i2.z, inv_mni = i2.w;
        float mjx = j0.x, mjy = j0.y, mjz = j0.z;
        float mnj = j1.z;
        int spj = (int)j1.w;
        float mhjx = j2.x, mhjy = j2.y, mhjz = j2.z;

        float d = sqrtf(rx * rx + ry * ry + rz * rz + 1e-9f);
        float invd = frcp(d);
        float rhx = rx * invd, rhy = ry * invd, rhz = rz * invd;

        float x = fminf(fmaxf(d * (1.f / 3.f) - 1.f, -1.f), 1.f);
        float x2 = 2.f * x;
        float T0 = 1.f, T1 = x;
        float T2 = x2 * T1 - T0, T3 = x2 * T2 - T1, T4 = x2 * T3 - T2, T5 = x2 * T4 - T3;
        float T6 = x2 * T5 - T4, T7 = x2 * T6 - T5, T8 = x2 * T7 - T6, T9 = x2 * T8 - T7;
        float T10 = x2 * T9 - T8, T11 = x2 * T10 - T9;
        float fcut = (d < 6.f) ? 0.5f * (__cosf(d * 0.52359877559829887f) + 1.f) : 0.f;

        const float* cr = chl + (spi * 4 + spj) * 100;
        float phi[8];
#pragma unroll
        for (int n = 0; n < 8; n++) {
            const float4* c4 = (const float4*)(cr + n * 12);
            float4 c0 = c4[0], c1 = c4[1], c2 = c4[2];
            float acc = c0.x * T0 + c0.y * T1 + c0.z * T2 + c0.w * T3;
            acc += c1.x * T4 + c1.y * T5 + c1.z * T6 + c1.w * T7;
            acc += c2.x * T8 + c2.y * T9 + c2.z * T10 + c2.w * T11;
            phi[n] = acc * fcut;
        }

        float w1 = mix * mjx + miy * mjy + miz * mjz;
        float dhi = mhix * rhx + mhiy * rhy + mhiz * rhz;
        float dhj = mhjx * rhx + mhjy * rhy + mhjz * rhz;
        float w2 = dhi * dhi, w3 = dhj * dhj;
        float cx = miy * mjz - miz * mjy;
        float cy = miz * mjx - mix * mjz;
        float cz = mix * mjy - miy * mjx;
        float w4 = rhx * cx + rhy * cy + rhz * cz;
        float w6 = w1 * inv_mni;      // (mhi.mhj)*mnj == (mi.mj)/mni
        float w7 = mnj * mnj;

        float* sa = segacc + il * SEGSTRIDE;
#pragma unroll
        for (int n = 0; n < 8; n++) {
            float p = phi[n];
            atomicAdd(&sa[0 * 8 + n], p);
            atomicAdd(&sa[1 * 8 + n], w1 * p);
            atomicAdd(&sa[2 * 8 + n], w2 * p);
            atomicAdd(&sa[3 * 8 + n], w3 * p);
            atomicAdd(&sa[4 * 8 + n], w4 * p);
            atomicAdd(&sa[5 * 8 + n], mnj * p);
            atomicAdd(&sa[6 * 8 + n], w6 * p);
            atomicAdd(&sa[7 * 8 + n], w7 * p);
            atomicAdd(&sa[64 + n * 3 + 0], p * rhx);
            atomicAdd(&sa[64 + n * 3 + 1], p * rhy);
            atomicAdd(&sa[64 + n * 3 + 2], p * rhz);
        }
    }
    __syncthreads();

    int il = t >> 3, s = t & 7;
    int a = abase + il;
    if (a < N_ATOMS) {
        float* o = segbuf + (size_t)a * 72;
        const float* sa = segacc + il * SEGSTRIDE;
#pragma unroll
        for (int r = 0; r < 8; r++) o[r * 8 + s] = sa[r * 8 + s];
        float vx = sa[64 + s * 3 + 0], vy = sa[64 + s * 3 + 1], vz = sa[64 + s * 3 + 2];
        o[64 + s] = vx * vx + vy * vy + vz * vz;
    }
}

// ---------------- merged tail MLPs: thread=atom, fully static unroll ----------------

__global__ __launch_bounds__(256) void k_tail(
    const float* __restrict__ segbuf, const float* __restrict__ packed,
    const int* __restrict__ species, const int* __restrict__ batch,
    const float* __restrict__ c1s, const float* __restrict__ c1m,
    const float* __restrict__ shift,
    const float* __restrict__ Ws1,
    const float* __restrict__ Ws2, const float* __restrict__ bs2,
    const float* __restrict__ Ws3, const float* __restrict__ bs3,
    const float* __restrict__ Wm1,
    const float* __restrict__ Wm2, const float* __restrict__ bm2,
    const float* __restrict__ Wm3, const float* __restrict__ bm3,
    float* __restrict__ out) {
    __shared__ float spart[NSTRUCT];
    int t = threadIdx.x;
    if (t < NSTRUCT) spart[t] = 0.f;
    __syncthreads();

    int a = blockIdx.x * 256 + t;
    if (a < N_ATOMS) {
        const float4* sb4 = (const float4*)(segbuf + (size_t)a * 72);
        int spi = species[a];

        // ---- structure MLP ----
        float4 v0 = sb4[0], v1 = sb4[1], v2 = sb4[16], v3 = sb4[17];
        float x[16] = {v0.x, v0.y, v0.z, v0.w, v1.x, v1.y, v1.z, v1.w,
                       v2.x, v2.y, v2.z, v2.w, v3.x, v3.y, v3.z, v3.w};
        float h1[64];
        const float4* cb4 = (const float4*)(c1s + spi * 64);
#pragma unroll
        for (int q = 0; q < 16; q++) {
            float4 c = cb4[q];
            h1[q * 4 + 0] = c.x; h1[q * 4 + 1] = c.y;
            h1[q * 4 + 2] = c.z; h1[q * 4 + 3] = c.w;
        }
#pragma unroll
        for (int k = 0; k < 16; k++) {
            float xv = x[k];
#pragma unroll
            for (int o = 0; o < 64; o++) h1[o] = fmaf(xv, Ws1[k * 64 + o], h1[o]);
        }
#pragma unroll
        for (int o = 0; o < 64; o++) h1[o] = silu(h1[o]);

        float e_at = bs3[0] + shift[spi];
#pragma unroll
        for (int cbk = 0; cbk < 4; cbk++) {
            float h2[16];
#pragma unroll
            for (int o = 0; o < 16; o++) h2[o] = bs2[cbk * 16 + o];
#pragma unroll
            for (int k = 0; k < 64; k++) {
                float xv = h1[k];
#pragma unroll
                for (int o = 0; o < 16; o++)
                    h2[o] = fmaf(xv, Ws2[k * 64 + cbk * 16 + o], h2[o]);
            }
#pragma unroll
            for (int o = 0; o < 16; o++)
                e_at = fmaf(silu(h2[o]), Ws3[cbk * 16 + o], e_at);
        }

        // ---- magnetic MLP, all 9 heads (h compile-time via full unroll) ----
        float amp = packed[a * 12 + 6];
#pragma unroll
        for (int h = 0; h < 9; h++) {
            const int kk = (h <= 5) ? h : (h - 1);
            float4 s0 = sb4[kk * 2], s1 = sb4[kk * 2 + 1];
            float sc = (h == 0 || h == 5) ? amp : 1.f;
            float xm[8] = {s0.x * sc, s0.y * sc, s0.z * sc, s0.w * sc,
                           s1.x * sc, s1.y * sc, s1.z * sc, s1.w * sc};

            float hm1[32];
            const float4* cm4 = (const float4*)(c1m + (h * 4 + spi) * 32);
#pragma unroll
            for (int q = 0; q < 8; q++) {
                float4 c = cm4[q];
                hm1[q * 4 + 0] = c.x; hm1[q * 4 + 1] = c.y;
                hm1[q * 4 + 2] = c.z; hm1[q * 4 + 3] = c.w;
            }
            const float* wb1 = Wm1 + h * 768;
#pragma unroll
            for (int d = 0; d < 8; d++) {
                float xv = xm[d];
#pragma unroll
                for (int o = 0; o < 32; o++) hm1[o] = fmaf(xv, wb1[d * 32 + o], hm1[o]);
            }
#pragma unroll
            for (int o = 0; o < 32; o++) hm1[o] = silu(hm1[o]);

            const float* wb2 = Wm2 + h * 1024;
            float e_head = bm3[h];
#pragma unroll
            for (int cbk = 0; cbk < 2; cbk++) {
                float h2[16];
#pragma unroll
                for (int o = 0; o < 16; o++) h2[o] = bm2[h * 32 + cbk * 16 + o];
#pragma unroll
                for (int d = 0; d < 32; d++) {
                    float xv = hm1[d];
#pragma unroll
                    for (int o = 0; o < 16; o++)
                        h2[o] = fmaf(xv, wb2[d * 32 + cbk * 16 + o], h2[o]);
                }
#pragma unroll
                for (int o = 0; o < 16; o++)
                    e_head = fmaf(silu(h2[o]), Wm3[h * 32 + cbk * 16 + o], e_head);
            }
            e_at += e_head;
        }
        atomicAdd(&spart[batch[a]], e_at);
    }
    __syncthreads();
    if (t < NSTRUCT) {
        float v = spart[t];
        if (v != 0.f) atomicAdd(&out[t], v);
    }
}

// ---------------- launch ----------------

extern "C" void kernel_launch(void* const* d_in, const int* in_sizes, int n_in,
                              void* d_out, int out_size, void* d_ws, size_t ws_size,
                              hipStream_t stream) {
    const float* pos   = (const float*)d_in[0];
    const float* mmv   = (const float*)d_in[1];
    const int* species = (const int*)d_in[2];
    const int* i_idx   = (const int*)d_in[3];
    const int* j_idx   = (const int*)d_in[4];
    const int* batch   = (const int*)d_in[5];
    const float* cheb  = (const float*)d_in[6];
    const float* embt  = (const float*)d_in[7];
    const float* shift = (const float*)d_in[8];
    const float* Ws1 = (const float*)d_in[9];
    const float* bs1 = (const float*)d_in[10];
    const float* Ws2 = (const float*)d_in[11];
    const float* bs2 = (const float*)d_in[12];
    const float* Ws3 = (const float*)d_in[13];
    const float* bs3 = (const float*)d_in[14];
    const float* Wm1 = (const float*)d_in[15];
    const float* bm1 = (const float*)d_in[16];
    const float* Wm2 = (const float*)d_in[17];
    const float* bm2 = (const float*)d_in[18];
    const float* Wm3 = (const float*)d_in[19];
    const float* bm3 = (const float*)d_in[20];
    float* out = (float*)d_out;

    char* ws = (char*)d_ws;
    int* bucket_count  = (int*)(ws + 0);          // 6.3 KB
    int* bucket_start  = (int*)(ws + 8192);       // 6.3 KB
    int* bucket_cursor = (int*)(ws + 16384);      // 6.3 KB
    float* c1m         = (float*)(ws + 24576);    // 4.6 KB
    float* c1s         = (float*)(ws + 29184);    // 1 KB
    float* packed      = (float*)(ws + 32768);    // 4.8 MB
    float* segbuf      = (float*)(ws + 4843520);  // 28.8 MB
    unsigned* vb       = (unsigned*)(ws + 33643520); // 6.4 MB (end ~40.0 MB)

    const int NB_ATOM = (N_ATOMS + 255) / 256;     // 391
    const int NB_EPB  = (N_EDGES + EPB - 1) / EPB; // 196

    hipMemsetAsync(bucket_count, 0, NBUCK * sizeof(int), stream);
    hipMemsetAsync(out, 0, NSTRUCT * sizeof(float), stream);

    k_pack<<<NB_ATOM, 256, 0, stream>>>(pos, mmv, species, packed);
    k_prep<<<6, 256, 0, stream>>>(embt, Wm1, bm1, Ws1, bs1, c1m, c1s);
    k_bhist<<<NB_EPB, 1024, 0, stream>>>(i_idx, bucket_count);
    k_bscan<<<1, 1024, 0, stream>>>(bucket_count, bucket_start, bucket_cursor);
    k_bscatter<<<NB_EPB, 1024, 0, stream>>>(i_idx, j_idx, bucket_cursor, vb);
    k_fused<<<NBUCK, 512, 0, stream>>>(bucket_start, bucket_count, vb, packed, cheb, segbuf);
    k_tail<<<NB_ATOM, 256, 0, stream>>>(segbuf, packed, species, batch, c1s, c1m, shift,
                                        Ws1, Ws2, bs2, Ws3, bs3,
                                        Wm1, Wm2, bm2, Wm3, bm3, out);
}

// Round 12
// 234.900 us; speedup vs baseline: 4.7721x; 4.7721x over previous
//
#include <hip/hip_runtime.h>
#include <math.h>

#define N_ATOMS 100000
#define N_EDGES 1600000
#define NSTRUCT 64
#define APB 64         // atoms per bucket
#define NBUCK 1563     // ceil(N_ATOMS/APB)
#define EPB 8192       // edges per block in bucket passes
#define BCAP 1536      // LDS j cap per bucket (mean 1024, std ~32)

__device__ __forceinline__ float frcp(float x) { return __builtin_amdgcn_rcpf(x); }
__device__ __forceinline__ float silu(float v) { return v * frcp(1.f + __expf(-v)); }

// ---------------- pack atom data: {m,p.x},{p.yz,mn,sp},{mhat,1/mn} (48B) ----------------

__global__ void k_pack(const float* __restrict__ pos, const float* __restrict__ mmv,
                       const int* __restrict__ species, float* __restrict__ packed) {
    int a = blockIdx.x * 256 + threadIdx.x;
    if (a >= N_ATOMS) return;
    float mx = mmv[a * 3 + 0], my = mmv[a * 3 + 1], mz = mmv[a * 3 + 2];
    float px = pos[a * 3 + 0], py = pos[a * 3 + 1], pz = pos[a * 3 + 2];
    float mn = sqrtf(mx * mx + my * my + mz * mz + 1e-9f);
    float inv = frcp(mn);
    float4* o = (float4*)packed;
    o[a * 3 + 0] = make_float4(mx, my, mz, px);
    o[a * 3 + 1] = make_float4(py, pz, mn, (float)species[a]);
    o[a * 3 + 2] = make_float4(mx * inv, my * inv, mz * inv, inv);
}

// ---------------- prep: fold emb @ W-layer1 (+bias) per (species/head) ----------------

__global__ void k_prep(const float* __restrict__ embt,
                       const float* __restrict__ Wm1, const float* __restrict__ bm1,
                       const float* __restrict__ Ws1, const float* __restrict__ bs1,
                       float* __restrict__ c1m, float* __restrict__ c1s) {
    int tid = blockIdx.x * 256 + threadIdx.x;
    if (tid < 1152) {
        int h = tid >> 7;
        int sp = (tid >> 5) & 3;
        int o = tid & 31;
        float c = bm1[h * 32 + o];
#pragma unroll
        for (int q = 0; q < 16; q++)
            c = fmaf(embt[sp * 16 + q], Wm1[(h * 24 + 8 + q) * 32 + o], c);
        c1m[tid] = c;
    } else if (tid < 1152 + 256) {
        int k = tid - 1152;
        int sp = k >> 6, o = k & 63;
        float c = bs1[o];
#pragma unroll
        for (int q = 0; q < 16; q++)
            c = fmaf(embt[sp * 16 + q], Ws1[(16 + q) * 64 + o], c);
        c1s[k] = c;
    }
}

// ---------------- bucket histogram ----------------

__global__ __launch_bounds__(1024) void k_bhist(const int* __restrict__ i_idx,
                                                int* __restrict__ bucket_count) {
    __shared__ int h[NBUCK];
    int t = threadIdx.x;
    for (int k = t; k < NBUCK; k += 1024) h[k] = 0;
    __syncthreads();
    int base = blockIdx.x * EPB;
    for (int k = t; k < EPB; k += 1024) {
        int e = base + k;
        if (e < N_EDGES) atomicAdd(&h[i_idx[e] >> 6], 1);
    }
    __syncthreads();
    for (int k = t; k < NBUCK; k += 1024)
        if (h[k]) atomicAdd(&bucket_count[k], h[k]);
}

// ---------------- scan bucket counts (2 elems/thread) ----------------

__global__ __launch_bounds__(1024) void k_bscan(const int* __restrict__ bucket_count,
                                                int* __restrict__ bucket_start,
                                                int* __restrict__ bucket_cursor) {
    __shared__ int sd[2048];
    int t = threadIdx.x;
    int i0 = t, i1 = t + 1024;
    int a0 = (i0 < NBUCK) ? bucket_count[i0] : 0;
    int a1 = (i1 < NBUCK) ? bucket_count[i1] : 0;
    sd[i0] = a0; sd[i1] = a1;
    __syncthreads();
    for (int off = 1; off < 2048; off <<= 1) {
        int v0 = (i0 >= off) ? sd[i0 - off] : 0;
        int v1 = (i1 >= off) ? sd[i1 - off] : 0;
        __syncthreads();
        sd[i0] += v0; sd[i1] += v1;
        __syncthreads();
    }
    if (i0 < NBUCK) { int ex = sd[i0] - a0; bucket_start[i0] = ex; bucket_cursor[i0] = ex; }
    if (i1 < NBUCK) { int ex = sd[i1] - a1; bucket_start[i1] = ex; bucket_cursor[i1] = ex; }
}

// ---------------- scatter packed (il<<17)|j into bucket-major order ----------------

__global__ __launch_bounds__(1024) void k_bscatter(const int* __restrict__ i_idx,
                                                   const int* __restrict__ j_idx,
                                                   int* __restrict__ bucket_cursor,
                                                   unsigned* __restrict__ vb) {
    __shared__ int h[NBUCK];
    __shared__ int gbase[NBUCK];
    int t = threadIdx.x;
    for (int k = t; k < NBUCK; k += 1024) h[k] = 0;
    __syncthreads();
    int base = blockIdx.x * EPB;
    for (int k = t; k < EPB; k += 1024) {
        int e = base + k;
        if (e < N_EDGES) atomicAdd(&h[i_idx[e] >> 6], 1);
    }
    __syncthreads();
    for (int k = t; k < NBUCK; k += 1024) {
        int c = h[k];
        gbase[k] = c ? atomicAdd(&bucket_cursor[k], c) : 0;
        h[k] = 0;   // reuse as local cursor
    }
    __syncthreads();
    for (int k = t; k < EPB; k += 1024) {
        int e = base + k;
        if (e < N_EDGES) {
            int i = i_idx[e];
            int b = i >> 6;
            int r = atomicAdd(&h[b], 1);
            vb[gbase[b] + r] = ((unsigned)(i & 63) << 17) | (unsigned)j_idx[e];
        }
    }
}

// ---------------- fused sort + edge compute + reduce: 2 lanes/atom, 4 columns/lane ----------------

__global__ __launch_bounds__(128) void k_fused(
    const int* __restrict__ bucket_start, const int* __restrict__ bucket_count,
    const unsigned* __restrict__ vb,
    const float* __restrict__ packed, const float* __restrict__ cheb,
    float* __restrict__ segbuf) {
    __shared__ int ac[APB];
    __shared__ int st[APB];
    __shared__ int rs[APB];
    __shared__ unsigned spj[BCAP];    // 6 KB (j only, sorted)
    __shared__ float4 apk[APB * 3];   // 3 KB (48B/atom)
    int b = blockIdx.x, t = threadIdx.x;
    int estart = bucket_start[b], nb = bucket_count[b];
    if (nb > BCAP) nb = BCAP;   // statistically impossible; guards LDS
    int abase = b * APB;
    const float4* pk4 = (const float4*)packed;

    for (int k = t; k < APB * 3; k += 128) {
        int a = abase + k / 3;
        apk[k] = (a < N_ATOMS) ? pk4[a * 3 + (k % 3)] : make_float4(0.f, 0.f, 1.f, 0.f);
    }
    if (t < APB) ac[t] = 0;
    __syncthreads();
    for (int k = t; k < nb; k += 128)
        atomicAdd(&ac[vb[estart + k] >> 17], 1);
    __syncthreads();
    if (t < APB) st[t] = ac[t];
    __syncthreads();
    for (int off = 1; off < APB; off <<= 1) {
        int v = 0;
        if (t < APB && t >= off) v = st[t - off];
        __syncthreads();
        if (t < APB) st[t] += v;
        __syncthreads();
    }
    if (t < APB) {
        int ex = st[t] - ac[t];
        rs[t] = ex;
        ac[t] = ex;   // reuse as cursor
    }
    __syncthreads();
    for (int k = t; k < nb; k += 128) {
        unsigned v = vb[estart + k];
        int r = atomicAdd(&ac[v >> 17], 1);
        spj[r] = v & 0x1FFFFu;
    }
    __syncthreads();

    // ---- reduce phase: 2 lanes/atom, lane s owns columns 4s..4s+3 ----
    int g = t >> 1, s = t & 1;
    int a = abase + g;
    if (a >= N_ATOMS) return;

    float4 i0 = apk[g * 3 + 0], i1 = apk[g * 3 + 1], i2 = apk[g * 3 + 2];
    float mix = i0.x, miy = i0.y, miz = i0.z;
    float pix = i0.w, piy = i1.x, piz = i1.y;
    int spi = (int)i1.w;
    float mhix = i2.x, mhiy = i2.y, mhiz = i2.z, inv_mni = i2.w;
    const float* cbase = cheb + spi * 4 * 96 + s * 48;  // columns 4s..4s+3

    float sg[8][4];
    float vc[4][3];
#pragma unroll
    for (int r = 0; r < 8; r++)
#pragma unroll
        for (int n = 0; n < 4; n++) sg[r][n] = 0.f;
#pragma unroll
    for (int n = 0; n < 4; n++) { vc[n][0] = 0.f; vc[n][1] = 0.f; vc[n][2] = 0.f; }

    int r0 = rs[g], r1 = st[g];
    int jn = (r0 < r1) ? (int)spj[r0] : 0;
    float4 j0n = pk4[jn * 3 + 0];
    float4 j1n = pk4[jn * 3 + 1];
    float4 j2n = pk4[jn * 3 + 2];
    for (int k = r0; k < r1; ++k) {
        float4 a0 = j0n, a1 = j1n, a2 = j2n;
        if (k + 1 < r1) {
            jn = (int)spj[k + 1];
            j0n = pk4[jn * 3 + 0];
            j1n = pk4[jn * 3 + 1];
            j2n = pk4[jn * 3 + 2];
        }
        float mjx = a0.x, mjy = a0.y, mjz = a0.z;
        float rx = a0.w - pix, ry = a1.x - piy, rz = a1.y - piz;
        float mnj = a1.z;
        int spj_sp = (int)a1.w;
        float mhjx = a2.x, mhjy = a2.y, mhjz = a2.z;

        const float4* c4 = (const float4*)(cbase + spj_sp * 96);

        float d = sqrtf(rx * rx + ry * ry + rz * rz + 1e-9f);
        float invd = frcp(d);
        float rhx = rx * invd, rhy = ry * invd, rhz = rz * invd;

        float x = fminf(fmaxf(d * (1.f / 3.f) - 1.f, -1.f), 1.f);
        float x2 = 2.f * x;
        float T0 = 1.f, T1 = x;
        float T2 = x2 * T1 - T0, T3 = x2 * T2 - T1, T4 = x2 * T3 - T2, T5 = x2 * T4 - T3;
        float T6 = x2 * T5 - T4, T7 = x2 * T6 - T5, T8 = x2 * T7 - T6, T9 = x2 * T8 - T7;
        float T10 = x2 * T9 - T8, T11 = x2 * T10 - T9;
        float fcut = (d < 6.f) ? 0.5f * (__cosf(d * 0.52359877559829887f) + 1.f) : 0.f;

        float phi[4];
#pragma unroll
        for (int n = 0; n < 4; n++) {
            float4 c0 = c4[n * 3 + 0], c1 = c4[n * 3 + 1], c2 = c4[n * 3 + 2];
            float acc = c0.x * T0 + c0.y * T1 + c0.z * T2 + c0.w * T3;
            acc += c1.x * T4 + c1.y * T5 + c1.z * T6 + c1.w * T7;
            acc += c2.x * T8 + c2.y * T9 + c2.z * T10 + c2.w * T11;
            phi[n] = acc * fcut;
        }

        float w1 = mix * mjx + miy * mjy + miz * mjz;
        float dhi = mhix * rhx + mhiy * rhy + mhiz * rhz;
        float dhj = mhjx * rhx + mhjy * rhy + mhjz * rhz;
        float w2 = dhi * dhi, w3 = dhj * dhj;
        float cx = miy * mjz - miz * mjy;
        float cy = miz * mjx - mix * mjz;
        float cz = mix * mjy - miy * mjx;
        float w4 = rhx * cx + rhy * cy + rhz * cz;
        float w6 = w1 * inv_mni;      // (mhi.mhj)*mnj == (mi.mj)/mni
        float w7 = mnj * mnj;

#pragma unroll
        for (int n = 0; n < 4; n++) {
            float p = phi[n];
            sg[0][n] += p;
            sg[1][n] = fmaf(w1, p, sg[1][n]);
            sg[2][n] = fmaf(w2, p, sg[2][n]);
            sg[3][n] = fmaf(w3, p, sg[3][n]);
            sg[4][n] = fmaf(w4, p, sg[4][n]);
            sg[5][n] = fmaf(mnj, p, sg[5][n]);
            sg[6][n] = fmaf(w6, p, sg[6][n]);
            sg[7][n] = fmaf(w7, p, sg[7][n]);
            vc[n][0] = fmaf(p, rhx, vc[n][0]);
            vc[n][1] = fmaf(p, rhy, vc[n][1]);
            vc[n][2] = fmaf(p, rhz, vc[n][2]);
        }
    }

    float* o = segbuf + (size_t)a * 72;
#pragma unroll
    for (int r = 0; r < 8; r++) {
        float4 v = make_float4(sg[r][0], sg[r][1], sg[r][2], sg[r][3]);
        *(float4*)(o + r * 8 + s * 4) = v;
    }
    float4 vn;
    vn.x = vc[0][0] * vc[0][0] + vc[0][1] * vc[0][1] + vc[0][2] * vc[0][2];
    vn.y = vc[1][0] * vc[1][0] + vc[1][1] * vc[1][1] + vc[1][2] * vc[1][2];
    vn.z = vc[2][0] * vc[2][0] + vc[2][1] * vc[2][1] + vc[2][2] * vc[2][2];
    vn.w = vc[3][0] * vc[3][0] + vc[3][1] * vc[3][1] + vc[3][2] * vc[3][2];
    *(float4*)(o + 64 + s * 4) = vn;
}

// ---------------- structure MLP: thread=atom, FULLY static unroll (round-10, known-good) ----------------

__global__ __launch_bounds__(256) void k_struct(
    const float* __restrict__ segbuf, const int* __restrict__ species,
    const int* __restrict__ batch, const float* __restrict__ c1s,
    const float* __restrict__ shift,
    const float* __restrict__ Ws1,
    const float* __restrict__ Ws2, const float* __restrict__ bs2,
    const float* __restrict__ Ws3, const float* __restrict__ bs3,
    float* __restrict__ out) {
    __shared__ float spart[NSTRUCT];
    int t = threadIdx.x;
    if (t < NSTRUCT) spart[t] = 0.f;
    __syncthreads();

    int a = blockIdx.x * 256 + t;
    if (a < N_ATOMS) {
        const float4* sb4 = (const float4*)(segbuf + (size_t)a * 72);
        float4 v0 = sb4[0], v1 = sb4[1];
        float4 v2 = sb4[16], v3 = sb4[17];
        int spi = species[a];
        float x[16] = {v0.x, v0.y, v0.z, v0.w, v1.x, v1.y, v1.z, v1.w,
                       v2.x, v2.y, v2.z, v2.w, v3.x, v3.y, v3.z, v3.w};

        float h1[64];
        const float4* cb4 = (const float4*)(c1s + spi * 64);
#pragma unroll
        for (int q = 0; q < 16; q++) {
            float4 c = cb4[q];
            h1[q * 4 + 0] = c.x; h1[q * 4 + 1] = c.y;
            h1[q * 4 + 2] = c.z; h1[q * 4 + 3] = c.w;
        }
#pragma unroll
        for (int k = 0; k < 16; k++) {
            float xv = x[k];
#pragma unroll
            for (int o = 0; o < 64; o++) h1[o] = fmaf(xv, Ws1[k * 64 + o], h1[o]);
        }
#pragma unroll
        for (int o = 0; o < 64; o++) h1[o] = silu(h1[o]);

        float e_struct = bs3[0] + shift[spi];
#pragma unroll
        for (int cbk = 0; cbk < 4; cbk++) {
            float h2[16];
#pragma unroll
            for (int o = 0; o < 16; o++) h2[o] = bs2[cbk * 16 + o];
#pragma unroll
            for (int k = 0; k < 64; k++) {
                float xv = h1[k];
#pragma unroll
                for (int o = 0; o < 16; o++)
                    h2[o] = fmaf(xv, Ws2[k * 64 + cbk * 16 + o], h2[o]);
            }
#pragma unroll
            for (int o = 0; o < 16; o++)
                e_struct = fmaf(silu(h2[o]), Ws3[cbk * 16 + o], e_struct);
        }
        atomicAdd(&spart[batch[a]], e_struct);
    }
    __syncthreads();
    if (t < NSTRUCT) {
        float v = spart[t];
        if (v != 0.f) atomicAdd(&out[t], v);
    }
}

// ---------------- magnetic MLP: thread=atom, head=blockIdx.y (round-10, known-good) ----------------

__global__ __launch_bounds__(256) void k_mag(
    const float* __restrict__ segbuf, const float* __restrict__ packed,
    const int* __restrict__ species, const int* __restrict__ batch,
    const float* __restrict__ c1m,
    const float* __restrict__ Wm1,
    const float* __restrict__ Wm2, const float* __restrict__ bm2,
    const float* __restrict__ Wm3, const float* __restrict__ bm3,
    float* __restrict__ out) {
    __shared__ float spart[NSTRUCT];
    int t = threadIdx.x;
    if (t < NSTRUCT) spart[t] = 0.f;
    __syncthreads();

    int h = blockIdx.y;                 // grid-uniform head index
    int a = blockIdx.x * 256 + t;
    if (a < N_ATOMS) {
        int kk = (h <= 5) ? h : (h - 1);
        const float4* sb4 = (const float4*)(segbuf + (size_t)a * 72 + kk * 8);
        float4 s0 = sb4[0], s1 = sb4[1];
        float amp = (h == 0 || h == 5) ? packed[a * 12 + 6] : 1.f;
        float x[8] = {s0.x * amp, s0.y * amp, s0.z * amp, s0.w * amp,
                      s1.x * amp, s1.y * amp, s1.z * amp, s1.w * amp};
        int spi = species[a];

        float hm1[32];
        const float4* cb4 = (const float4*)(c1m + (h * 4 + spi) * 32);
#pragma unroll
        for (int q = 0; q < 8; q++) {
            float4 c = cb4[q];
            hm1[q * 4 + 0] = c.x; hm1[q * 4 + 1] = c.y;
            hm1[q * 4 + 2] = c.z; hm1[q * 4 + 3] = c.w;
        }
        const float* wb1 = Wm1 + h * 768;
#pragma unroll
        for (int d = 0; d < 8; d++) {
            float xv = x[d];
#pragma unroll
            for (int o = 0; o < 32; o++) hm1[o] = fmaf(xv, wb1[d * 32 + o], hm1[o]);
        }
#pragma unroll
        for (int o = 0; o < 32; o++) hm1[o] = silu(hm1[o]);

        const float* wb2 = Wm2 + h * 1024;
        float e_head = bm3[h];
#pragma unroll
        for (int cbk = 0; cbk < 2; cbk++) {
            float h2[16];
#pragma unroll
            for (int o = 0; o < 16; o++) h2[o] = bm2[h * 32 + cbk * 16 + o];
#pragma unroll
            for (int d = 0; d < 32; d++) {
                float xv = hm1[d];
#pragma unroll
                for (int o = 0; o < 16; o++)
                    h2[o] = fmaf(xv, wb2[d * 32 + cbk * 16 + o], h2[o]);
            }
#pragma unroll
            for (int o = 0; o < 16; o++)
                e_head = fmaf(silu(h2[o]), Wm3[h * 32 + cbk * 16 + o], e_head);
        }
        atomicAdd(&spart[batch[a]], e_head);
    }
    __syncthreads();
    if (t < NSTRUCT) {
        float v = spart[t];
        if (v != 0.f) atomicAdd(&out[t], v);
    }
}

// ---------------- launch ----------------

extern "C" void kernel_launch(void* const* d_in, const int* in_sizes, int n_in,
                              void* d_out, int out_size, void* d_ws, size_t ws_size,
                              hipStream_t stream) {
    const float* pos   = (const float*)d_in[0];
    const float* mmv   = (const float*)d_in[1];
    const int* species = (const int*)d_in[2];
    const int* i_idx   = (const int*)d_in[3];
    const int* j_idx   = (const int*)d_in[4];
    const int* batch   = (const int*)d_in[5];
    const float* cheb  = (const float*)d_in[6];
    const float* embt  = (const float*)d_in[7];
    const float* shift = (const float*)d_in[8];
    const float* Ws1 = (const float*)d_in[9];
    const float* bs1 = (const float*)d_in[10];
    const float* Ws2 = (const float*)d_in[11];
    const float* bs2 = (const float*)d_in[12];
    const float* Ws3 = (const float*)d_in[13];
    const float* bs3 = (const float*)d_in[14];
    const float* Wm1 = (const float*)d_in[15];
    const float* bm1 = (const float*)d_in[16];
    const float* Wm2 = (const float*)d_in[17];
    const float* bm2 = (const float*)d_in[18];
    const float* Wm3 = (const float*)d_in[19];
    const float* bm3 = (const float*)d_in[20];
    float* out = (float*)d_out;

    char* ws = (char*)d_ws;
    int* bucket_count  = (int*)(ws + 0);          // 6.3 KB
    int* bucket_start  = (int*)(ws + 8192);       // 6.3 KB
    int* bucket_cursor = (int*)(ws + 16384);      // 6.3 KB
    float* c1m         = (float*)(ws + 24576);    // 4.6 KB
    float* c1s         = (float*)(ws + 29184);    // 1 KB
    float* packed      = (float*)(ws + 32768);    // 4.8 MB
    float* segbuf      = (float*)(ws + 4843520);  // 28.8 MB
    unsigned* vb       = (unsigned*)(ws + 33643520); // 6.4 MB (end ~40.0 MB)

    const int NB_ATOM = (N_ATOMS + 255) / 256;     // 391
    const int NB_EPB  = (N_EDGES + EPB - 1) / EPB; // 196

    hipMemsetAsync(bucket_count, 0, NBUCK * sizeof(int), stream);
    hipMemsetAsync(out, 0, NSTRUCT * sizeof(float), stream);

    k_pack<<<NB_ATOM, 256, 0, stream>>>(pos, mmv, species, packed);
    k_prep<<<6, 256, 0, stream>>>(embt, Wm1, bm1, Ws1, bs1, c1m, c1s);
    k_bhist<<<NB_EPB, 1024, 0, stream>>>(i_idx, bucket_count);
    k_bscan<<<1, 1024, 0, stream>>>(bucket_count, bucket_start, bucket_cursor);
    k_bscatter<<<NB_EPB, 1024, 0, stream>>>(i_idx, j_idx, bucket_cursor, vb);
    k_fused<<<NBUCK, 128, 0, stream>>>(bucket_start, bucket_count, vb, packed, cheb, segbuf);
    k_struct<<<NB_ATOM, 256, 0, stream>>>(segbuf, species, batch, c1s, shift,
                                          Ws1, Ws2, bs2, Ws3, bs3, out);
    dim3 magGrid(NB_ATOM, 9);
    k_mag<<<magGrid, 256, 0, stream>>>(segbuf, packed, species, batch, c1m,
                                       Wm1, Wm2, bm2, Wm3, bm3, out);
}

// Round 13
// 212.272 us; speedup vs baseline: 5.2809x; 1.1066x over previous
//
#include <hip/hip_runtime.h>
#include <math.h>

#define N_ATOMS 100000
#define N_EDGES 1600000
#define NSTRUCT 64
#define APB 64         // atoms per bucket
#define NBUCK 1563     // ceil(N_ATOMS/APB)
#define EPB 8192       // edges per block in scatter pass
#define BCAP 1536      // fixed bucket capacity (mean 1024, std ~32 -> +16 sigma)

__device__ __forceinline__ float frcp(float x) { return __builtin_amdgcn_rcpf(x); }
__device__ __forceinline__ float silu(float v) { return v * frcp(1.f + __expf(-v)); }

// ---------------- pack atom data: {m,p.x},{p.yz,mn,sp},{mhat,1/mn} (48B) ----------------

__global__ void k_pack(const float* __restrict__ pos, const float* __restrict__ mmv,
                       const int* __restrict__ species, float* __restrict__ packed) {
    int a = blockIdx.x * 256 + threadIdx.x;
    if (a >= N_ATOMS) return;
    float mx = mmv[a * 3 + 0], my = mmv[a * 3 + 1], mz = mmv[a * 3 + 2];
    float px = pos[a * 3 + 0], py = pos[a * 3 + 1], pz = pos[a * 3 + 2];
    float mn = sqrtf(mx * mx + my * my + mz * mz + 1e-9f);
    float inv = frcp(mn);
    float4* o = (float4*)packed;
    o[a * 3 + 0] = make_float4(mx, my, mz, px);
    o[a * 3 + 1] = make_float4(py, pz, mn, (float)species[a]);
    o[a * 3 + 2] = make_float4(mx * inv, my * inv, mz * inv, inv);
}

// ---------------- prep: fold emb @ W-layer1 (+bias) per (species/head) ----------------

__global__ void k_prep(const float* __restrict__ embt,
                       const float* __restrict__ Wm1, const float* __restrict__ bm1,
                       const float* __restrict__ Ws1, const float* __restrict__ bs1,
                       float* __restrict__ c1m, float* __restrict__ c1s) {
    int tid = blockIdx.x * 256 + threadIdx.x;
    if (tid < 1152) {
        int h = tid >> 7;
        int sp = (tid >> 5) & 3;
        int o = tid & 31;
        float c = bm1[h * 32 + o];
#pragma unroll
        for (int q = 0; q < 16; q++)
            c = fmaf(embt[sp * 16 + q], Wm1[(h * 24 + 8 + q) * 32 + o], c);
        c1m[tid] = c;
    } else if (tid < 1152 + 256) {
        int k = tid - 1152;
        int sp = k >> 6, o = k & 63;
        float c = bs1[o];
#pragma unroll
        for (int q = 0; q < 16; q++)
            c = fmaf(embt[sp * 16 + q], Ws1[(16 + q) * 64 + o], c);
        c1s[k] = c;
    }
}

// ---------------- scatter (il<<17)|j into fixed-capacity bucket slots ----------------

__global__ __launch_bounds__(1024) void k_bscatter(const int* __restrict__ i_idx,
                                                   const int* __restrict__ j_idx,
                                                   int* __restrict__ bucket_cursor,
                                                   unsigned* __restrict__ vb) {
    __shared__ int h[NBUCK];
    __shared__ int gbase[NBUCK];
    int t = threadIdx.x;
    for (int k = t; k < NBUCK; k += 1024) h[k] = 0;
    __syncthreads();
    int base = blockIdx.x * EPB;
    for (int k = t; k < EPB; k += 1024) {
        int e = base + k;
        if (e < N_EDGES) atomicAdd(&h[i_idx[e] >> 6], 1);
    }
    __syncthreads();
    for (int k = t; k < NBUCK; k += 1024) {
        int c = h[k];
        gbase[k] = c ? atomicAdd(&bucket_cursor[k], c) : 0;
        h[k] = 0;   // reuse as local cursor
    }
    __syncthreads();
    for (int k = t; k < EPB; k += 1024) {
        int e = base + k;
        if (e < N_EDGES) {
            int i = i_idx[e];
            int b = i >> 6;
            int r = gbase[b] + atomicAdd(&h[b], 1);
            if (r < BCAP)
                vb[b * BCAP + r] = ((unsigned)(i & 63) << 17) | (unsigned)j_idx[e];
        }
    }
}

// ---------------- fused sort + edge compute + reduce: 4 lanes/atom, 2 columns/lane ----------------

__global__ __launch_bounds__(256) void k_fused(
    const int* __restrict__ bucket_cursor,
    const unsigned* __restrict__ vb,
    const float* __restrict__ packed, const float* __restrict__ cheb,
    float* __restrict__ segbuf) {
    __shared__ int ac[APB];
    __shared__ int st[APB];
    __shared__ int rs[APB];
    __shared__ unsigned spj[BCAP];    // 6 KB (j only, sorted by owner atom)
    __shared__ float4 apk[APB * 3];   // 3 KB (48B/atom)
    int b = blockIdx.x, t = threadIdx.x;
    int nb = bucket_cursor[b];
    if (nb > BCAP) nb = BCAP;
    int estart = b * BCAP;
    int abase = b * APB;
    const float4* pk4 = (const float4*)packed;

    for (int k = t; k < APB * 3; k += 256) {
        int a = abase + k / 3;
        apk[k] = (a < N_ATOMS) ? pk4[a * 3 + (k % 3)] : make_float4(0.f, 0.f, 1.f, 0.f);
    }
    if (t < APB) ac[t] = 0;
    __syncthreads();
    for (int k = t; k < nb; k += 256)
        atomicAdd(&ac[vb[estart + k] >> 17], 1);
    __syncthreads();
    if (t < APB) st[t] = ac[t];
    __syncthreads();
    for (int off = 1; off < APB; off <<= 1) {
        int v = 0;
        if (t < APB && t >= off) v = st[t - off];
        __syncthreads();
        if (t < APB) st[t] += v;
        __syncthreads();
    }
    if (t < APB) {
        int ex = st[t] - ac[t];
        rs[t] = ex;
        ac[t] = ex;   // reuse as cursor
    }
    __syncthreads();
    for (int k = t; k < nb; k += 256) {
        unsigned v = vb[estart + k];
        int r = atomicAdd(&ac[v >> 17], 1);
        spj[r] = v & 0x1FFFFu;
    }
    __syncthreads();

    // ---- reduce phase: 4 lanes/atom, lane s owns columns 2s, 2s+1 ----
    int g = t >> 2, s = t & 3;
    int a = abase + g;
    if (a >= N_ATOMS) return;

    float4 i0 = apk[g * 3 + 0], i1 = apk[g * 3 + 1], i2 = apk[g * 3 + 2];
    float mix = i0.x, miy = i0.y, miz = i0.z;
    float pix = i0.w, piy = i1.x, piz = i1.y;
    int spi = (int)i1.w;
    float mhix = i2.x, mhiy = i2.y, mhiz = i2.z, inv_mni = i2.w;
    const float* cbase = cheb + spi * 4 * 96 + s * 24;  // columns 2s, 2s+1

    float sg[8][2];
    float vc[2][3];
#pragma unroll
    for (int r = 0; r < 8; r++) { sg[r][0] = 0.f; sg[r][1] = 0.f; }
#pragma unroll
    for (int n = 0; n < 2; n++) { vc[n][0] = 0.f; vc[n][1] = 0.f; vc[n][2] = 0.f; }

    auto edge = [&](float4 a0, float4 a1, float4 a2) {
        float mjx = a0.x, mjy = a0.y, mjz = a0.z;
        float rx = a0.w - pix, ry = a1.x - piy, rz = a1.y - piz;
        float mnj = a1.z;
        int spj_sp = (int)a1.w;
        float mhjx = a2.x, mhjy = a2.y, mhjz = a2.z;

        const float4* c4 = (const float4*)(cbase + spj_sp * 96);
        float4 c00 = c4[0], c01 = c4[1], c02 = c4[2];
        float4 c10 = c4[3], c11 = c4[4], c12 = c4[5];

        float d = sqrtf(rx * rx + ry * ry + rz * rz + 1e-9f);
        float invd = frcp(d);
        float rhx = rx * invd, rhy = ry * invd, rhz = rz * invd;

        float x = fminf(fmaxf(d * (1.f / 3.f) - 1.f, -1.f), 1.f);
        float x2 = 2.f * x;
        float T0 = 1.f, T1 = x;
        float T2 = x2 * T1 - T0, T3 = x2 * T2 - T1, T4 = x2 * T3 - T2, T5 = x2 * T4 - T3;
        float T6 = x2 * T5 - T4, T7 = x2 * T6 - T5, T8 = x2 * T7 - T6, T9 = x2 * T8 - T7;
        float T10 = x2 * T9 - T8, T11 = x2 * T10 - T9;
        float fcut = (d < 6.f) ? 0.5f * (__cosf(d * 0.52359877559829887f) + 1.f) : 0.f;

        float p0 = c00.x * T0 + c00.y * T1 + c00.z * T2 + c00.w * T3
                 + c01.x * T4 + c01.y * T5 + c01.z * T6 + c01.w * T7
                 + c02.x * T8 + c02.y * T9 + c02.z * T10 + c02.w * T11;
        float p1 = c10.x * T0 + c10.y * T1 + c10.z * T2 + c10.w * T3
                 + c11.x * T4 + c11.y * T5 + c11.z * T6 + c11.w * T7
                 + c12.x * T8 + c12.y * T9 + c12.z * T10 + c12.w * T11;
        p0 *= fcut; p1 *= fcut;

        float w1 = mix * mjx + miy * mjy + miz * mjz;
        float dhi = mhix * rhx + mhiy * rhy + mhiz * rhz;
        float dhj = mhjx * rhx + mhjy * rhy + mhjz * rhz;
        float w2 = dhi * dhi, w3 = dhj * dhj;
        float cx = miy * mjz - miz * mjy;
        float cy = miz * mjx - mix * mjz;
        float cz = mix * mjy - miy * mjx;
        float w4 = rhx * cx + rhy * cy + rhz * cz;
        float w6 = w1 * inv_mni;      // (mhi.mhj)*mnj == (mi.mj)/mni
        float w7 = mnj * mnj;

        sg[0][0] += p0;                      sg[0][1] += p1;
        sg[1][0] = fmaf(w1, p0, sg[1][0]);   sg[1][1] = fmaf(w1, p1, sg[1][1]);
        sg[2][0] = fmaf(w2, p0, sg[2][0]);   sg[2][1] = fmaf(w2, p1, sg[2][1]);
        sg[3][0] = fmaf(w3, p0, sg[3][0]);   sg[3][1] = fmaf(w3, p1, sg[3][1]);
        sg[4][0] = fmaf(w4, p0, sg[4][0]);   sg[4][1] = fmaf(w4, p1, sg[4][1]);
        sg[5][0] = fmaf(mnj, p0, sg[5][0]);  sg[5][1] = fmaf(mnj, p1, sg[5][1]);
        sg[6][0] = fmaf(w6, p0, sg[6][0]);   sg[6][1] = fmaf(w6, p1, sg[6][1]);
        sg[7][0] = fmaf(w7, p0, sg[7][0]);   sg[7][1] = fmaf(w7, p1, sg[7][1]);
        vc[0][0] = fmaf(p0, rhx, vc[0][0]);  vc[1][0] = fmaf(p1, rhx, vc[1][0]);
        vc[0][1] = fmaf(p0, rhy, vc[0][1]);  vc[1][1] = fmaf(p1, rhy, vc[1][1]);
        vc[0][2] = fmaf(p0, rhz, vc[0][2]);  vc[1][2] = fmaf(p1, rhz, vc[1][2]);
    };

    int r0 = rs[g], r1 = st[g];
    int k = r0;
    for (; k + 1 < r1; k += 2) {
        int ja = (int)spj[k], jb = (int)spj[k + 1];
        float4 x0 = pk4[ja * 3 + 0], x1 = pk4[ja * 3 + 1], x2 = pk4[ja * 3 + 2];
        float4 y0 = pk4[jb * 3 + 0], y1 = pk4[jb * 3 + 1], y2 = pk4[jb * 3 + 2];
        edge(x0, x1, x2);
        edge(y0, y1, y2);
    }
    if (k < r1) {
        int ja = (int)spj[k];
        edge(pk4[ja * 3 + 0], pk4[ja * 3 + 1], pk4[ja * 3 + 2]);
    }

    float* o = segbuf + (size_t)a * 72;
#pragma unroll
    for (int r = 0; r < 8; r++)
        *(float2*)(o + r * 8 + s * 2) = make_float2(sg[r][0], sg[r][1]);
    float2 vn;
    vn.x = vc[0][0] * vc[0][0] + vc[0][1] * vc[0][1] + vc[0][2] * vc[0][2];
    vn.y = vc[1][0] * vc[1][0] + vc[1][1] * vc[1][1] + vc[1][2] * vc[1][2];
    *(float2*)(o + 64 + s * 2) = vn;
}

// ---------------- structure MLP: thread=atom, FULLY static unroll (known-good) ----------------

__global__ __launch_bounds__(256) void k_struct(
    const float* __restrict__ segbuf, const int* __restrict__ species,
    const int* __restrict__ batch, const float* __restrict__ c1s,
    const float* __restrict__ shift,
    const float* __restrict__ Ws1,
    const float* __restrict__ Ws2, const float* __restrict__ bs2,
    const float* __restrict__ Ws3, const float* __restrict__ bs3,
    float* __restrict__ out) {
    __shared__ float spart[NSTRUCT];
    int t = threadIdx.x;
    if (t < NSTRUCT) spart[t] = 0.f;
    __syncthreads();

    int a = blockIdx.x * 256 + t;
    if (a < N_ATOMS) {
        const float4* sb4 = (const float4*)(segbuf + (size_t)a * 72);
        float4 v0 = sb4[0], v1 = sb4[1];
        float4 v2 = sb4[16], v3 = sb4[17];
        int spi = species[a];
        float x[16] = {v0.x, v0.y, v0.z, v0.w, v1.x, v1.y, v1.z, v1.w,
                       v2.x, v2.y, v2.z, v2.w, v3.x, v3.y, v3.z, v3.w};

        float h1[64];
        const float4* cb4 = (const float4*)(c1s + spi * 64);
#pragma unroll
        for (int q = 0; q < 16; q++) {
            float4 c = cb4[q];
            h1[q * 4 + 0] = c.x; h1[q * 4 + 1] = c.y;
            h1[q * 4 + 2] = c.z; h1[q * 4 + 3] = c.w;
        }
#pragma unroll
        for (int k = 0; k < 16; k++) {
            float xv = x[k];
#pragma unroll
            for (int o = 0; o < 64; o++) h1[o] = fmaf(xv, Ws1[k * 64 + o], h1[o]);
        }
#pragma unroll
        for (int o = 0; o < 64; o++) h1[o] = silu(h1[o]);

        float e_struct = bs3[0] + shift[spi];
#pragma unroll
        for (int cbk = 0; cbk < 4; cbk++) {
            float h2[16];
#pragma unroll
            for (int o = 0; o < 16; o++) h2[o] = bs2[cbk * 16 + o];
#pragma unroll
            for (int k = 0; k < 64; k++) {
                float xv = h1[k];
#pragma unroll
                for (int o = 0; o < 16; o++)
                    h2[o] = fmaf(xv, Ws2[k * 64 + cbk * 16 + o], h2[o]);
            }
#pragma unroll
            for (int o = 0; o < 16; o++)
                e_struct = fmaf(silu(h2[o]), Ws3[cbk * 16 + o], e_struct);
        }
        atomicAdd(&spart[batch[a]], e_struct);
    }
    __syncthreads();
    if (t < NSTRUCT) {
        float v = spart[t];
        if (v != 0.f) atomicAdd(&out[t], v);
    }
}

// ---------------- magnetic MLP: thread=atom, head=blockIdx.y (known-good) ----------------

__global__ __launch_bounds__(256) void k_mag(
    const float* __restrict__ segbuf, const float* __restrict__ packed,
    const int* __restrict__ species, const int* __restrict__ batch,
    const float* __restrict__ c1m,
    const float* __restrict__ Wm1,
    const float* __restrict__ Wm2, const float* __restrict__ bm2,
    const float* __restrict__ Wm3, const float* __restrict__ bm3,
    float* __restrict__ out) {
    __shared__ float spart[NSTRUCT];
    int t = threadIdx.x;
    if (t < NSTRUCT) spart[t] = 0.f;
    __syncthreads();

    int h = blockIdx.y;                 // grid-uniform head index
    int a = blockIdx.x * 256 + t;
    if (a < N_ATOMS) {
        int kk = (h <= 5) ? h : (h - 1);
        const float4* sb4 = (const float4*)(segbuf + (size_t)a * 72 + kk * 8);
        float4 s0 = sb4[0], s1 = sb4[1];
        float amp = (h == 0 || h == 5) ? packed[a * 12 + 6] : 1.f;
        float x[8] = {s0.x * amp, s0.y * amp, s0.z * amp, s0.w * amp,
                      s1.x * amp, s1.y * amp, s1.z * amp, s1.w * amp};
        int spi = species[a];

        float hm1[32];
        const float4* cb4 = (const float4*)(c1m + (h * 4 + spi) * 32);
#pragma unroll
        for (int q = 0; q < 8; q++) {
            float4 c = cb4[q];
            hm1[q * 4 + 0] = c.x; hm1[q * 4 + 1] = c.y;
            hm1[q * 4 + 2] = c.z; hm1[q * 4 + 3] = c.w;
        }
        const float* wb1 = Wm1 + h * 768;
#pragma unroll
        for (int d = 0; d < 8; d++) {
            float xv = x[d];
#pragma unroll
            for (int o = 0; o < 32; o++) hm1[o] = fmaf(xv, wb1[d * 32 + o], hm1[o]);
        }
#pragma unroll
        for (int o = 0; o < 32; o++) hm1[o] = silu(hm1[o]);

        const float* wb2 = Wm2 + h * 1024;
        float e_head = bm3[h];
#pragma unroll
        for (int cbk = 0; cbk < 2; cbk++) {
            float h2[16];
#pragma unroll
            for (int o = 0; o < 16; o++) h2[o] = bm2[h * 32 + cbk * 16 + o];
#pragma unroll
            for (int d = 0; d < 32; d++) {
                float xv = hm1[d];
#pragma unroll
                for (int o = 0; o < 16; o++)
                    h2[o] = fmaf(xv, wb2[d * 32 + cbk * 16 + o], h2[o]);
            }
#pragma unroll
            for (int o = 0; o < 16; o++)
                e_head = fmaf(silu(h2[o]), Wm3[h * 32 + cbk * 16 + o], e_head);
        }
        atomicAdd(&spart[batch[a]], e_head);
    }
    __syncthreads();
    if (t < NSTRUCT) {
        float v = spart[t];
        if (v != 0.f) atomicAdd(&out[t], v);
    }
}

// ---------------- launch ----------------

extern "C" void kernel_launch(void* const* d_in, const int* in_sizes, int n_in,
                              void* d_out, int out_size, void* d_ws, size_t ws_size,
                              hipStream_t stream) {
    const float* pos   = (const float*)d_in[0];
    const float* mmv   = (const float*)d_in[1];
    const int* species = (const int*)d_in[2];
    const int* i_idx   = (const int*)d_in[3];
    const int* j_idx   = (const int*)d_in[4];
    const int* batch   = (const int*)d_in[5];
    const float* cheb  = (const float*)d_in[6];
    const float* embt  = (const float*)d_in[7];
    const float* shift = (const float*)d_in[8];
    const float* Ws1 = (const float*)d_in[9];
    const float* bs1 = (const float*)d_in[10];
    const float* Ws2 = (const float*)d_in[11];
    const float* bs2 = (const float*)d_in[12];
    const float* Ws3 = (const float*)d_in[13];
    const float* bs3 = (const float*)d_in[14];
    const float* Wm1 = (const float*)d_in[15];
    const float* bm1 = (const float*)d_in[16];
    const float* Wm2 = (const float*)d_in[17];
    const float* bm2 = (const float*)d_in[18];
    const float* Wm3 = (const float*)d_in[19];
    const float* bm3 = (const float*)d_in[20];
    float* out = (float*)d_out;

    char* ws = (char*)d_ws;
    int* bucket_cursor = (int*)(ws + 0);          // 6.3 KB (zeroed)
    float* c1m         = (float*)(ws + 8192);     // 4.6 KB
    float* c1s         = (float*)(ws + 16384);    // 1 KB
    float* packed      = (float*)(ws + 20480);    // 4.8 MB
    float* segbuf      = (float*)(ws + 4820480);  // 28.8 MB
    unsigned* vb       = (unsigned*)(ws + 33620480); // 9.6 MB (end ~43.2 MB)

    const int NB_ATOM = (N_ATOMS + 255) / 256;     // 391
    const int NB_EPB  = (N_EDGES + EPB - 1) / EPB; // 196

    hipMemsetAsync(bucket_cursor, 0, NBUCK * sizeof(int), stream);
    hipMemsetAsync(out, 0, NSTRUCT * sizeof(float), stream);

    k_pack<<<NB_ATOM, 256, 0, stream>>>(pos, mmv, species, packed);
    k_prep<<<6, 256, 0, stream>>>(embt, Wm1, bm1, Ws1, bs1, c1m, c1s);
    k_bscatter<<<NB_EPB, 1024, 0, stream>>>(i_idx, j_idx, bucket_cursor, vb);
    k_fused<<<NBUCK, 256, 0, stream>>>(bucket_cursor, vb, packed, cheb, segbuf);
    k_struct<<<NB_ATOM, 256, 0, stream>>>(segbuf, species, batch, c1s, shift,
                                          Ws1, Ws2, bs2, Ws3, bs3, out);
    dim3 magGrid(NB_ATOM, 9);
    k_mag<<<magGrid, 256, 0, stream>>>(segbuf, packed, species, batch, c1m,
                                       Wm1, Wm2, bm2, Wm3, bm3, out);
}

// Round 14
// 201.461 us; speedup vs baseline: 5.5642x; 1.0537x over previous
//
#include <hip/hip_runtime.h>
#include <math.h>

#define N_ATOMS 100000
#define N_EDGES 1600000
#define NSTRUCT 64
#define APB 64         // atoms per bucket
#define NBUCK 1563     // ceil(N_ATOMS/APB)
#define EPB 8192       // edges per block in scatter pass
#define BCAP 1536      // fixed bucket capacity (mean 1024, std ~32 -> +16 sigma)
#define PLANE 800000   // N_ATOMS * 8 floats per segbuf plane

__device__ __forceinline__ float frcp(float x) { return __builtin_amdgcn_rcpf(x); }
__device__ __forceinline__ float silu(float v) { return v * frcp(1.f + __expf(-v)); }

// ---------------- pack atom data (32B): {m.xyz,p.x},{p.yz,mn,sp} ----------------

__global__ void k_pack(const float* __restrict__ pos, const float* __restrict__ mmv,
                       const int* __restrict__ species, float* __restrict__ packed) {
    int a = blockIdx.x * 256 + threadIdx.x;
    if (a >= N_ATOMS) return;
    float mx = mmv[a * 3 + 0], my = mmv[a * 3 + 1], mz = mmv[a * 3 + 2];
    float px = pos[a * 3 + 0], py = pos[a * 3 + 1], pz = pos[a * 3 + 2];
    float mn = sqrtf(mx * mx + my * my + mz * mz + 1e-9f);
    float4* o = (float4*)packed;
    o[a * 2 + 0] = make_float4(mx, my, mz, px);
    o[a * 2 + 1] = make_float4(py, pz, mn, (float)species[a]);
}

// ---------------- prep: fold emb @ W-layer1 (+bias) per (species/head) ----------------

__global__ void k_prep(const float* __restrict__ embt,
                       const float* __restrict__ Wm1, const float* __restrict__ bm1,
                       const float* __restrict__ Ws1, const float* __restrict__ bs1,
                       float* __restrict__ c1m, float* __restrict__ c1s) {
    int tid = blockIdx.x * 256 + threadIdx.x;
    if (tid < 1152) {
        int h = tid >> 7;
        int sp = (tid >> 5) & 3;
        int o = tid & 31;
        float c = bm1[h * 32 + o];
#pragma unroll
        for (int q = 0; q < 16; q++)
            c = fmaf(embt[sp * 16 + q], Wm1[(h * 24 + 8 + q) * 32 + o], c);
        c1m[tid] = c;
    } else if (tid < 1152 + 256) {
        int k = tid - 1152;
        int sp = k >> 6, o = k & 63;
        float c = bs1[o];
#pragma unroll
        for (int q = 0; q < 16; q++)
            c = fmaf(embt[sp * 16 + q], Ws1[(16 + q) * 64 + o], c);
        c1s[k] = c;
    }
}

// ---------------- scatter (il<<17)|j into fixed-capacity bucket slots ----------------

__global__ __launch_bounds__(1024) void k_bscatter(const int* __restrict__ i_idx,
                                                   const int* __restrict__ j_idx,
                                                   int* __restrict__ bucket_cursor,
                                                   unsigned* __restrict__ vb) {
    __shared__ int h[NBUCK];
    __shared__ int gbase[NBUCK];
    int t = threadIdx.x;
    for (int k = t; k < NBUCK; k += 1024) h[k] = 0;
    __syncthreads();
    int base = blockIdx.x * EPB;
    for (int k = t; k < EPB; k += 1024) {
        int e = base + k;
        if (e < N_EDGES) atomicAdd(&h[i_idx[e] >> 6], 1);
    }
    __syncthreads();
    for (int k = t; k < NBUCK; k += 1024) {
        int c = h[k];
        gbase[k] = c ? atomicAdd(&bucket_cursor[k], c) : 0;
        h[k] = 0;   // reuse as local cursor
    }
    __syncthreads();
    for (int k = t; k < EPB; k += 1024) {
        int e = base + k;
        if (e < N_EDGES) {
            int i = i_idx[e];
            int b = i >> 6;
            int r = gbase[b] + atomicAdd(&h[b], 1);
            if (r < BCAP)
                vb[b * BCAP + r] = ((unsigned)(i & 63) << 17) | (unsigned)j_idx[e];
        }
    }
}

// ---------------- fused sort + edge compute + reduce: 4 lanes/atom, 2 columns/lane ----------------
// writes plane-major segbuf: plane r in [0,8) = seg row r, plane 8 = |vec|^2; [a][col] 8 floats

__global__ __launch_bounds__(256) void k_fused(
    const int* __restrict__ bucket_cursor,
    const unsigned* __restrict__ vb,
    const float* __restrict__ packed, const float* __restrict__ cheb,
    float* __restrict__ segbuf) {
    __shared__ int ac[APB];
    __shared__ int st[APB];
    __shared__ int rs[APB];
    __shared__ unsigned spj[BCAP];    // 6 KB (j only, sorted by owner atom)
    __shared__ float4 apk[APB * 2];   // 2 KB (32B/atom)
    int b = blockIdx.x, t = threadIdx.x;
    int nb = bucket_cursor[b];
    if (nb > BCAP) nb = BCAP;
    int estart = b * BCAP;
    int abase = b * APB;
    const float4* pk4 = (const float4*)packed;

    for (int k = t; k < APB * 2; k += 256) {
        int a = abase + (k >> 1);
        apk[k] = (a < N_ATOMS) ? pk4[a * 2 + (k & 1)] : make_float4(0.f, 0.f, 1.f, 0.f);
    }
    if (t < APB) ac[t] = 0;
    __syncthreads();
    for (int k = t; k < nb; k += 256)
        atomicAdd(&ac[vb[estart + k] >> 17], 1);
    __syncthreads();
    if (t < APB) st[t] = ac[t];
    __syncthreads();
    for (int off = 1; off < APB; off <<= 1) {
        int v = 0;
        if (t < APB && t >= off) v = st[t - off];
        __syncthreads();
        if (t < APB) st[t] += v;
        __syncthreads();
    }
    if (t < APB) {
        int ex = st[t] - ac[t];
        rs[t] = ex;
        ac[t] = ex;   // reuse as cursor
    }
    __syncthreads();
    for (int k = t; k < nb; k += 256) {
        unsigned v = vb[estart + k];
        int r = atomicAdd(&ac[v >> 17], 1);
        spj[r] = v & 0x1FFFFu;
    }
    __syncthreads();

    // ---- reduce phase: 4 lanes/atom, lane s owns columns 2s, 2s+1 ----
    int g = t >> 2, s = t & 3;
    int a = abase + g;
    if (a >= N_ATOMS) return;

    float4 i0 = apk[g * 2 + 0], i1 = apk[g * 2 + 1];
    float mix = i0.x, miy = i0.y, miz = i0.z;
    float pix = i0.w, piy = i1.x, piz = i1.y;
    float mni = i1.z;
    int spi = (int)i1.w;
    float inv_mni = frcp(mni);
    float mhix = mix * inv_mni, mhiy = miy * inv_mni, mhiz = miz * inv_mni;
    const float* cbase = cheb + spi * 4 * 96 + s * 24;  // columns 2s, 2s+1

    float sg[8][2];
    float vc[2][3];
#pragma unroll
    for (int r = 0; r < 8; r++) { sg[r][0] = 0.f; sg[r][1] = 0.f; }
#pragma unroll
    for (int n = 0; n < 2; n++) { vc[n][0] = 0.f; vc[n][1] = 0.f; vc[n][2] = 0.f; }

    auto edge = [&](float4 a0, float4 a1) {
        float mjx = a0.x, mjy = a0.y, mjz = a0.z;
        float rx = a0.w - pix, ry = a1.x - piy, rz = a1.y - piz;
        float mnj = a1.z;
        int spj_sp = (int)a1.w;

        const float4* c4 = (const float4*)(cbase + spj_sp * 96);
        float4 c00 = c4[0], c01 = c4[1], c02 = c4[2];
        float4 c10 = c4[3], c11 = c4[4], c12 = c4[5];

        float d = sqrtf(rx * rx + ry * ry + rz * rz + 1e-9f);
        float invd = frcp(d);
        float rhx = rx * invd, rhy = ry * invd, rhz = rz * invd;

        float x = fminf(fmaxf(d * (1.f / 3.f) - 1.f, -1.f), 1.f);
        float x2 = 2.f * x;
        float T0 = 1.f, T1 = x;
        float T2 = x2 * T1 - T0, T3 = x2 * T2 - T1, T4 = x2 * T3 - T2, T5 = x2 * T4 - T3;
        float T6 = x2 * T5 - T4, T7 = x2 * T6 - T5, T8 = x2 * T7 - T6, T9 = x2 * T8 - T7;
        float T10 = x2 * T9 - T8, T11 = x2 * T10 - T9;
        float fcut = (d < 6.f) ? 0.5f * (__cosf(d * 0.52359877559829887f) + 1.f) : 0.f;

        float p0 = c00.x * T0 + c00.y * T1 + c00.z * T2 + c00.w * T3
                 + c01.x * T4 + c01.y * T5 + c01.z * T6 + c01.w * T7
                 + c02.x * T8 + c02.y * T9 + c02.z * T10 + c02.w * T11;
        float p1 = c10.x * T0 + c10.y * T1 + c10.z * T2 + c10.w * T3
                 + c11.x * T4 + c11.y * T5 + c11.z * T6 + c11.w * T7
                 + c12.x * T8 + c12.y * T9 + c12.z * T10 + c12.w * T11;
        p0 *= fcut; p1 *= fcut;

        float invmnj = frcp(mnj);
        float w1 = mix * mjx + miy * mjy + miz * mjz;
        float dhi = mhix * rhx + mhiy * rhy + mhiz * rhz;
        float dhj = (mjx * rhx + mjy * rhy + mjz * rhz) * invmnj;
        float w2 = dhi * dhi, w3 = dhj * dhj;
        float cx = miy * mjz - miz * mjy;
        float cy = miz * mjx - mix * mjz;
        float cz = mix * mjy - miy * mjx;
        float w4 = rhx * cx + rhy * cy + rhz * cz;
        float w6 = w1 * inv_mni;      // (mhi.mhj)*mnj == (mi.mj)/mni
        float w7 = mnj * mnj;

        sg[0][0] += p0;                      sg[0][1] += p1;
        sg[1][0] = fmaf(w1, p0, sg[1][0]);   sg[1][1] = fmaf(w1, p1, sg[1][1]);
        sg[2][0] = fmaf(w2, p0, sg[2][0]);   sg[2][1] = fmaf(w2, p1, sg[2][1]);
        sg[3][0] = fmaf(w3, p0, sg[3][0]);   sg[3][1] = fmaf(w3, p1, sg[3][1]);
        sg[4][0] = fmaf(w4, p0, sg[4][0]);   sg[4][1] = fmaf(w4, p1, sg[4][1]);
        sg[5][0] = fmaf(mnj, p0, sg[5][0]);  sg[5][1] = fmaf(mnj, p1, sg[5][1]);
        sg[6][0] = fmaf(w6, p0, sg[6][0]);   sg[6][1] = fmaf(w6, p1, sg[6][1]);
        sg[7][0] = fmaf(w7, p0, sg[7][0]);   sg[7][1] = fmaf(w7, p1, sg[7][1]);
        vc[0][0] = fmaf(p0, rhx, vc[0][0]);  vc[1][0] = fmaf(p1, rhx, vc[1][0]);
        vc[0][1] = fmaf(p0, rhy, vc[0][1]);  vc[1][1] = fmaf(p1, rhy, vc[1][1]);
        vc[0][2] = fmaf(p0, rhz, vc[0][2]);  vc[1][2] = fmaf(p1, rhz, vc[1][2]);
    };

    int r0 = rs[g], r1 = st[g];
    int k = r0;
    for (; k + 1 < r1; k += 2) {
        int ja = (int)spj[k], jb = (int)spj[k + 1];
        float4 x0 = pk4[ja * 2 + 0], x1 = pk4[ja * 2 + 1];
        float4 y0 = pk4[jb * 2 + 0], y1 = pk4[jb * 2 + 1];
        edge(x0, x1);
        edge(y0, y1);
    }
    if (k < r1) {
        int ja = (int)spj[k];
        edge(pk4[ja * 2 + 0], pk4[ja * 2 + 1]);
    }

    // plane-major writes: coalesced 32B runs per 16-atom wave-group per plane
#pragma unroll
    for (int r = 0; r < 8; r++)
        *(float2*)(segbuf + r * PLANE + a * 8 + s * 2) = make_float2(sg[r][0], sg[r][1]);
    float2 vn;
    vn.x = vc[0][0] * vc[0][0] + vc[0][1] * vc[0][1] + vc[0][2] * vc[0][2];
    vn.y = vc[1][0] * vc[1][0] + vc[1][1] * vc[1][1] + vc[1][2] * vc[1][2];
    *(float2*)(segbuf + 8 * PLANE + a * 8 + s * 2) = vn;
}

// ---------------- structure MLP: thread=atom, dense plane reads ----------------

__global__ __launch_bounds__(256) void k_struct(
    const float* __restrict__ segbuf, const int* __restrict__ species,
    const int* __restrict__ batch, const float* __restrict__ c1s,
    const float* __restrict__ shift,
    const float* __restrict__ Ws1,
    const float* __restrict__ Ws2, const float* __restrict__ bs2,
    const float* __restrict__ Ws3, const float* __restrict__ bs3,
    float* __restrict__ out) {
    __shared__ float spart[NSTRUCT];
    int t = threadIdx.x;
    if (t < NSTRUCT) spart[t] = 0.f;
    __syncthreads();

    int a = blockIdx.x * 256 + t;
    if (a < N_ATOMS) {
        const float4* pa = (const float4*)(segbuf + 0 * PLANE + a * 8);
        const float4* pv = (const float4*)(segbuf + 8 * PLANE + a * 8);
        float4 v0 = pa[0], v1 = pa[1];
        float4 v2 = pv[0], v3 = pv[1];
        int spi = species[a];
        float x[16] = {v0.x, v0.y, v0.z, v0.w, v1.x, v1.y, v1.z, v1.w,
                       v2.x, v2.y, v2.z, v2.w, v3.x, v3.y, v3.z, v3.w};

        float h1[64];
        const float4* cb4 = (const float4*)(c1s + spi * 64);
#pragma unroll
        for (int q = 0; q < 16; q++) {
            float4 c = cb4[q];
            h1[q * 4 + 0] = c.x; h1[q * 4 + 1] = c.y;
            h1[q * 4 + 2] = c.z; h1[q * 4 + 3] = c.w;
        }
#pragma unroll
        for (int k = 0; k < 16; k++) {
            float xv = x[k];
#pragma unroll
            for (int o = 0; o < 64; o++) h1[o] = fmaf(xv, Ws1[k * 64 + o], h1[o]);
        }
#pragma unroll
        for (int o = 0; o < 64; o++) h1[o] = silu(h1[o]);

        float e_struct = bs3[0] + shift[spi];
#pragma unroll
        for (int cbk = 0; cbk < 4; cbk++) {
            float h2[16];
#pragma unroll
            for (int o = 0; o < 16; o++) h2[o] = bs2[cbk * 16 + o];
#pragma unroll
            for (int k = 0; k < 64; k++) {
                float xv = h1[k];
#pragma unroll
                for (int o = 0; o < 16; o++)
                    h2[o] = fmaf(xv, Ws2[k * 64 + cbk * 16 + o], h2[o]);
            }
#pragma unroll
            for (int o = 0; o < 16; o++)
                e_struct = fmaf(silu(h2[o]), Ws3[cbk * 16 + o], e_struct);
        }
        atomicAdd(&spart[batch[a]], e_struct);
    }
    __syncthreads();
    if (t < NSTRUCT) {
        float v = spart[t];
        if (v != 0.f) atomicAdd(&out[t], v);
    }
}

// ---------------- magnetic MLP: thread=atom, head=blockIdx.y, dense plane reads ----------------

__global__ __launch_bounds__(256) void k_mag(
    const float* __restrict__ segbuf, const float* __restrict__ packed,
    const int* __restrict__ species, const int* __restrict__ batch,
    const float* __restrict__ c1m,
    const float* __restrict__ Wm1,
    const float* __restrict__ Wm2, const float* __restrict__ bm2,
    const float* __restrict__ Wm3, const float* __restrict__ bm3,
    float* __restrict__ out) {
    __shared__ float spart[NSTRUCT];
    int t = threadIdx.x;
    if (t < NSTRUCT) spart[t] = 0.f;
    __syncthreads();

    int h = blockIdx.y;                 // grid-uniform head index
    int a = blockIdx.x * 256 + t;
    if (a < N_ATOMS) {
        int kk = (h <= 5) ? h : (h - 1);
        const float4* pk_ = (const float4*)(segbuf + kk * PLANE + a * 8);
        float4 s0 = pk_[0], s1 = pk_[1];
        float amp = (h == 0 || h == 5) ? packed[a * 8 + 6] : 1.f;
        float x[8] = {s0.x * amp, s0.y * amp, s0.z * amp, s0.w * amp,
                      s1.x * amp, s1.y * amp, s1.z * amp, s1.w * amp};
        int spi = species[a];

        float hm1[32];
        const float4* cb4 = (const float4*)(c1m + (h * 4 + spi) * 32);
#pragma unroll
        for (int q = 0; q < 8; q++) {
            float4 c = cb4[q];
            hm1[q * 4 + 0] = c.x; hm1[q * 4 + 1] = c.y;
            hm1[q * 4 + 2] = c.z; hm1[q * 4 + 3] = c.w;
        }
        const float* wb1 = Wm1 + h * 768;
#pragma unroll
        for (int d = 0; d < 8; d++) {
            float xv = x[d];
#pragma unroll
            for (int o = 0; o < 32; o++) hm1[o] = fmaf(xv, wb1[d * 32 + o], hm1[o]);
        }
#pragma unroll
        for (int o = 0; o < 32; o++) hm1[o] = silu(hm1[o]);

        const float* wb2 = Wm2 + h * 1024;
        float e_head = bm3[h];
#pragma unroll
        for (int cbk = 0; cbk < 2; cbk++) {
            float h2[16];
#pragma unroll
            for (int o = 0; o < 16; o++) h2[o] = bm2[h * 32 + cbk * 16 + o];
#pragma unroll
            for (int d = 0; d < 32; d++) {
                float xv = hm1[d];
#pragma unroll
                for (int o = 0; o < 16; o++)
                    h2[o] = fmaf(xv, wb2[d * 32 + cbk * 16 + o], h2[o]);
            }
#pragma unroll
            for (int o = 0; o < 16; o++)
                e_head = fmaf(silu(h2[o]), Wm3[h * 32 + cbk * 16 + o], e_head);
        }
        atomicAdd(&spart[batch[a]], e_head);
    }
    __syncthreads();
    if (t < NSTRUCT) {
        float v = spart[t];
        if (v != 0.f) atomicAdd(&out[t], v);
    }
}

// ---------------- launch ----------------

extern "C" void kernel_launch(void* const* d_in, const int* in_sizes, int n_in,
                              void* d_out, int out_size, void* d_ws, size_t ws_size,
                              hipStream_t stream) {
    const float* pos   = (const float*)d_in[0];
    const float* mmv   = (const float*)d_in[1];
    const int* species = (const int*)d_in[2];
    const int* i_idx   = (const int*)d_in[3];
    const int* j_idx   = (const int*)d_in[4];
    const int* batch   = (const int*)d_in[5];
    const float* cheb  = (const float*)d_in[6];
    const float* embt  = (const float*)d_in[7];
    const float* shift = (const float*)d_in[8];
    const float* Ws1 = (const float*)d_in[9];
    const float* bs1 = (const float*)d_in[10];
    const float* Ws2 = (const float*)d_in[11];
    const float* bs2 = (const float*)d_in[12];
    const float* Ws3 = (const float*)d_in[13];
    const float* bs3 = (const float*)d_in[14];
    const float* Wm1 = (const float*)d_in[15];
    const float* bm1 = (const float*)d_in[16];
    const float* Wm2 = (const float*)d_in[17];
    const float* bm2 = (const float*)d_in[18];
    const float* Wm3 = (const float*)d_in[19];
    const float* bm3 = (const float*)d_in[20];
    float* out = (float*)d_out;

    char* ws = (char*)d_ws;
    int* bucket_cursor = (int*)(ws + 0);          // 6.3 KB (zeroed)
    float* c1m         = (float*)(ws + 8192);     // 4.6 KB
    float* c1s         = (float*)(ws + 16384);    // 1 KB
    float* packed      = (float*)(ws + 20480);    // 3.2 MB
    float* segbuf      = (float*)(ws + 3220480);  // 28.8 MB (9 planes x 3.2 MB)
    unsigned* vb       = (unsigned*)(ws + 32020480); // 9.6 MB (end ~41.6 MB)

    const int NB_ATOM = (N_ATOMS + 255) / 256;     // 391
    const int NB_EPB  = (N_EDGES + EPB - 1) / EPB; // 196

    hipMemsetAsync(bucket_cursor, 0, NBUCK * sizeof(int), stream);
    hipMemsetAsync(out, 0, NSTRUCT * sizeof(float), stream);

    k_pack<<<NB_ATOM, 256, 0, stream>>>(pos, mmv, species, packed);
    k_prep<<<6, 256, 0, stream>>>(embt, Wm1, bm1, Ws1, bs1, c1m, c1s);
    k_bscatter<<<NB_EPB, 1024, 0, stream>>>(i_idx, j_idx, bucket_cursor, vb);
    k_fused<<<NBUCK, 256, 0, stream>>>(bucket_cursor, vb, packed, cheb, segbuf);
    k_struct<<<NB_ATOM, 256, 0, stream>>>(segbuf, species, batch, c1s, shift,
                                          Ws1, Ws2, bs2, Ws3, bs3, out);
    dim3 magGrid(NB_ATOM, 9);
    k_mag<<<magGrid, 256, 0, stream>>>(segbuf, packed, species, batch, c1m,
                                       Wm1, Wm2, bm2, Wm3, bm3, out);
}

// Round 15
// 191.172 us; speedup vs baseline: 5.8637x; 1.0538x over previous
//
#include <hip/hip_runtime.h>
#include <math.h>

#define N_ATOMS 100000
#define N_EDGES 1600000
#define NSTRUCT 64
#define APB 64         // atoms per bucket (= one wave in the scan)
#define NBUCK 1563     // ceil(N_ATOMS/APB)
#define EPB 8192       // edges per block in scatter pass
#define BCAP 1536      // fixed bucket capacity (mean 1024, std ~32 -> +16 sigma)
#define PLANE 800000   // N_ATOMS * 8 floats per segbuf plane

__device__ __forceinline__ float frcp(float x) { return __builtin_amdgcn_rcpf(x); }
__device__ __forceinline__ float silu(float v) { return v * frcp(1.f + __expf(-v)); }

// ---------------- pack atom data (32B) + fold emb@W-layer1 prep ----------------

__global__ void k_pack(const float* __restrict__ pos, const float* __restrict__ mmv,
                       const int* __restrict__ species, float* __restrict__ packed,
                       const float* __restrict__ embt,
                       const float* __restrict__ Wm1, const float* __restrict__ bm1,
                       const float* __restrict__ Ws1, const float* __restrict__ bs1,
                       float* __restrict__ c1m, float* __restrict__ c1s) {
    int tid = blockIdx.x * 256 + threadIdx.x;
    if (tid < N_ATOMS) {
        int a = tid;
        float mx = mmv[a * 3 + 0], my = mmv[a * 3 + 1], mz = mmv[a * 3 + 2];
        float px = pos[a * 3 + 0], py = pos[a * 3 + 1], pz = pos[a * 3 + 2];
        float mn = sqrtf(mx * mx + my * my + mz * mz + 1e-9f);
        float4* o = (float4*)packed;
        o[a * 2 + 0] = make_float4(mx, my, mz, px);
        o[a * 2 + 1] = make_float4(py, pz, mn, (float)species[a]);
    }
    if (tid < 1152) {
        int h = tid >> 7;
        int sp = (tid >> 5) & 3;
        int o = tid & 31;
        float c = bm1[h * 32 + o];
#pragma unroll
        for (int q = 0; q < 16; q++)
            c = fmaf(embt[sp * 16 + q], Wm1[(h * 24 + 8 + q) * 32 + o], c);
        c1m[tid] = c;
    } else if (tid < 1152 + 256) {
        int k = tid - 1152;
        int sp = k >> 6, o = k & 63;
        float c = bs1[o];
#pragma unroll
        for (int q = 0; q < 16; q++)
            c = fmaf(embt[sp * 16 + q], Ws1[(16 + q) * 64 + o], c);
        c1s[k] = c;
    }
}

// ---------------- scatter (il<<17)|j into fixed-capacity bucket slots ----------------

__global__ __launch_bounds__(1024) void k_bscatter(const int* __restrict__ i_idx,
                                                   const int* __restrict__ j_idx,
                                                   int* __restrict__ bucket_cursor,
                                                   unsigned* __restrict__ vb) {
    __shared__ int h[NBUCK];
    __shared__ int gbase[NBUCK];
    int t = threadIdx.x;
    for (int k = t; k < NBUCK; k += 1024) h[k] = 0;
    __syncthreads();
    int base = blockIdx.x * EPB;
    for (int k = t; k < EPB; k += 1024) {
        int e = base + k;
        if (e < N_EDGES) atomicAdd(&h[i_idx[e] >> 6], 1);
    }
    __syncthreads();
    for (int k = t; k < NBUCK; k += 1024) {
        int c = h[k];
        gbase[k] = c ? atomicAdd(&bucket_cursor[k], c) : 0;
        h[k] = 0;   // reuse as local cursor
    }
    __syncthreads();
    for (int k = t; k < EPB; k += 1024) {
        int e = base + k;
        if (e < N_EDGES) {
            int i = i_idx[e];
            int b = i >> 6;
            int r = gbase[b] + atomicAdd(&h[b], 1);
            if (r < BCAP)
                vb[b * BCAP + r] = ((unsigned)(i & 63) << 17) | (unsigned)j_idx[e];
        }
    }
}

// ---------------- fused sort + edge compute + reduce: 4 lanes/atom, 2 columns/lane ----------------

__global__ __launch_bounds__(256) void k_fused(
    const int* __restrict__ bucket_cursor,
    const unsigned* __restrict__ vb,
    const float* __restrict__ packed, const float* __restrict__ cheb,
    float* __restrict__ segbuf) {
    __shared__ int ac[APB];
    __shared__ int st[APB];
    __shared__ int rs[APB];
    __shared__ unsigned spj[BCAP];    // 6 KB (j only, sorted by owner atom)
    __shared__ float4 apk[APB * 2];   // 2 KB (32B/atom)
    int b = blockIdx.x, t = threadIdx.x;
    int nb = bucket_cursor[b];
    if (nb > BCAP) nb = BCAP;
    int estart = b * BCAP;
    int abase = b * APB;
    const float4* pk4 = (const float4*)packed;

    for (int k = t; k < APB * 2; k += 256) {
        int a = abase + (k >> 1);
        apk[k] = (a < N_ATOMS) ? pk4[a * 2 + (k & 1)] : make_float4(0.f, 0.f, 1.f, 0.f);
    }
    if (t < APB) ac[t] = 0;
    __syncthreads();
    for (int k = t; k < nb; k += 256)
        atomicAdd(&ac[vb[estart + k] >> 17], 1);
    __syncthreads();
    if (t < APB) {   // single-wave inclusive scan (APB==64: threads 0..63 = wave 0)
        int c = ac[t];
        int sum = c;
#pragma unroll
        for (int off = 1; off < 64; off <<= 1) {
            int v = __shfl_up(sum, off, 64);
            if (t >= off) sum += v;
        }
        st[t] = sum;
        rs[t] = sum - c;
        ac[t] = sum - c;   // reuse as cursor
    }
    __syncthreads();
    for (int k = t; k < nb; k += 256) {
        unsigned v = vb[estart + k];
        int r = atomicAdd(&ac[v >> 17], 1);
        spj[r] = v & 0x1FFFFu;
    }
    __syncthreads();

    // ---- reduce phase: 4 lanes/atom, lane s owns columns 2s, 2s+1 ----
    int g = t >> 2, s = t & 3;
    int a = abase + g;
    if (a >= N_ATOMS) return;

    float4 i0 = apk[g * 2 + 0], i1 = apk[g * 2 + 1];
    float mix = i0.x, miy = i0.y, miz = i0.z;
    float pix = i0.w, piy = i1.x, piz = i1.y;
    float mni = i1.z;
    int spi = (int)i1.w;
    float inv_mni = frcp(mni);
    float mhix = mix * inv_mni, mhiy = miy * inv_mni, mhiz = miz * inv_mni;
    const float* cbase = cheb + spi * 4 * 96 + s * 24;  // columns 2s, 2s+1

    float sg[8][2];
    float vc[2][3];
#pragma unroll
    for (int r = 0; r < 8; r++) { sg[r][0] = 0.f; sg[r][1] = 0.f; }
#pragma unroll
    for (int n = 0; n < 2; n++) { vc[n][0] = 0.f; vc[n][1] = 0.f; vc[n][2] = 0.f; }

    auto edge = [&](float4 a0, float4 a1) {
        float mjx = a0.x, mjy = a0.y, mjz = a0.z;
        float rx = a0.w - pix, ry = a1.x - piy, rz = a1.y - piz;
        float mnj = a1.z;
        int spj_sp = (int)a1.w;

        const float4* c4 = (const float4*)(cbase + spj_sp * 96);
        float4 c00 = c4[0], c01 = c4[1], c02 = c4[2];
        float4 c10 = c4[3], c11 = c4[4], c12 = c4[5];

        float d = sqrtf(rx * rx + ry * ry + rz * rz + 1e-9f);
        float invd = frcp(d);
        float rhx = rx * invd, rhy = ry * invd, rhz = rz * invd;

        float x = fminf(fmaxf(d * (1.f / 3.f) - 1.f, -1.f), 1.f);
        float x2 = 2.f * x;
        float T0 = 1.f, T1 = x;
        float T2 = x2 * T1 - T0, T3 = x2 * T2 - T1, T4 = x2 * T3 - T2, T5 = x2 * T4 - T3;
        float T6 = x2 * T5 - T4, T7 = x2 * T6 - T5, T8 = x2 * T7 - T6, T9 = x2 * T8 - T7;
        float T10 = x2 * T9 - T8, T11 = x2 * T10 - T9;
        float fcut = (d < 6.f) ? 0.5f * (__cosf(d * 0.52359877559829887f) + 1.f) : 0.f;

        float p0 = c00.x * T0 + c00.y * T1 + c00.z * T2 + c00.w * T3
                 + c01.x * T4 + c01.y * T5 + c01.z * T6 + c01.w * T7
                 + c02.x * T8 + c02.y * T9 + c02.z * T10 + c02.w * T11;
        float p1 = c10.x * T0 + c10.y * T1 + c10.z * T2 + c10.w * T3
                 + c11.x * T4 + c11.y * T5 + c11.z * T6 + c11.w * T7
                 + c12.x * T8 + c12.y * T9 + c12.z * T10 + c12.w * T11;
        p0 *= fcut; p1 *= fcut;

        float invmnj = frcp(mnj);
        float w1 = mix * mjx + miy * mjy + miz * mjz;
        float dhi = mhix * rhx + mhiy * rhy + mhiz * rhz;
        float dhj = (mjx * rhx + mjy * rhy + mjz * rhz) * invmnj;
        float w2 = dhi * dhi, w3 = dhj * dhj;
        float cx = miy * mjz - miz * mjy;
        float cy = miz * mjx - mix * mjz;
        float cz = mix * mjy - miy * mjx;
        float w4 = rhx * cx + rhy * cy + rhz * cz;
        float w6 = w1 * inv_mni;      // (mhi.mhj)*mnj == (mi.mj)/mni
        float w7 = mnj * mnj;

        sg[0][0] += p0;                      sg[0][1] += p1;
        sg[1][0] = fmaf(w1, p0, sg[1][0]);   sg[1][1] = fmaf(w1, p1, sg[1][1]);
        sg[2][0] = fmaf(w2, p0, sg[2][0]);   sg[2][1] = fmaf(w2, p1, sg[2][1]);
        sg[3][0] = fmaf(w3, p0, sg[3][0]);   sg[3][1] = fmaf(w3, p1, sg[3][1]);
        sg[4][0] = fmaf(w4, p0, sg[4][0]);   sg[4][1] = fmaf(w4, p1, sg[4][1]);
        sg[5][0] = fmaf(mnj, p0, sg[5][0]);  sg[5][1] = fmaf(mnj, p1, sg[5][1]);
        sg[6][0] = fmaf(w6, p0, sg[6][0]);   sg[6][1] = fmaf(w6, p1, sg[6][1]);
        sg[7][0] = fmaf(w7, p0, sg[7][0]);   sg[7][1] = fmaf(w7, p1, sg[7][1]);
        vc[0][0] = fmaf(p0, rhx, vc[0][0]);  vc[1][0] = fmaf(p1, rhx, vc[1][0]);
        vc[0][1] = fmaf(p0, rhy, vc[0][1]);  vc[1][1] = fmaf(p1, rhy, vc[1][1]);
        vc[0][2] = fmaf(p0, rhz, vc[0][2]);  vc[1][2] = fmaf(p1, rhz, vc[1][2]);
    };

    int r0 = rs[g], r1 = st[g];
    // software pipeline: prefetch next pair while computing current pair
    int k = r0;
    int ja = (k < r1) ? (int)spj[k] : 0;
    int jb = (k + 1 < r1) ? (int)spj[k + 1] : 0;
    float4 x0 = pk4[ja * 2 + 0], x1 = pk4[ja * 2 + 1];
    float4 y0 = pk4[jb * 2 + 0], y1 = pk4[jb * 2 + 1];
    for (; k + 1 < r1; ) {
        int kn = k + 2;
        int jna = (kn < r1) ? (int)spj[kn] : 0;
        int jnb = (kn + 1 < r1) ? (int)spj[kn + 1] : 0;
        float4 nx0 = pk4[jna * 2 + 0], nx1 = pk4[jna * 2 + 1];
        float4 ny0 = pk4[jnb * 2 + 0], ny1 = pk4[jnb * 2 + 1];
        edge(x0, x1);
        edge(y0, y1);
        x0 = nx0; x1 = nx1; y0 = ny0; y1 = ny1;
        k = kn;
    }
    if (k < r1) edge(x0, x1);

    // plane-major writes: coalesced 32B runs per 16-atom wave-group per plane
#pragma unroll
    for (int r = 0; r < 8; r++)
        *(float2*)(segbuf + r * PLANE + a * 8 + s * 2) = make_float2(sg[r][0], sg[r][1]);
    float2 vn;
    vn.x = vc[0][0] * vc[0][0] + vc[0][1] * vc[0][1] + vc[0][2] * vc[0][2];
    vn.y = vc[1][0] * vc[1][0] + vc[1][1] * vc[1][1] + vc[1][2] * vc[1][2];
    *(float2*)(segbuf + 8 * PLANE + a * 8 + s * 2) = vn;
}

// ---------------- merged tail: grid.y<9 = mag head, grid.y==9 = struct MLP ----------------

__global__ __launch_bounds__(256) void k_tail(
    const float* __restrict__ segbuf, const float* __restrict__ packed,
    const int* __restrict__ species, const int* __restrict__ batch,
    const float* __restrict__ c1s, const float* __restrict__ c1m,
    const float* __restrict__ shift,
    const float* __restrict__ Ws1,
    const float* __restrict__ Ws2, const float* __restrict__ bs2,
    const float* __restrict__ Ws3, const float* __restrict__ bs3,
    const float* __restrict__ Wm1,
    const float* __restrict__ Wm2, const float* __restrict__ bm2,
    const float* __restrict__ Wm3, const float* __restrict__ bm3,
    float* __restrict__ out) {
    __shared__ float spart[NSTRUCT];
    int t = threadIdx.x;
    if (t < NSTRUCT) spart[t] = 0.f;
    __syncthreads();

    int a = blockIdx.x * 256 + t;
    int y = blockIdx.y;
    if (a < N_ATOMS) {
        int spi = species[a];
        float e_acc;
        if (y == 9) {
            // ---- structure MLP ----
            const float4* pa = (const float4*)(segbuf + 0 * PLANE + a * 8);
            const float4* pv = (const float4*)(segbuf + 8 * PLANE + a * 8);
            float4 v0 = pa[0], v1 = pa[1];
            float4 v2 = pv[0], v3 = pv[1];
            float x[16] = {v0.x, v0.y, v0.z, v0.w, v1.x, v1.y, v1.z, v1.w,
                           v2.x, v2.y, v2.z, v2.w, v3.x, v3.y, v3.z, v3.w};

            float h1[64];
            const float4* cb4 = (const float4*)(c1s + spi * 64);
#pragma unroll
            for (int q = 0; q < 16; q++) {
                float4 c = cb4[q];
                h1[q * 4 + 0] = c.x; h1[q * 4 + 1] = c.y;
                h1[q * 4 + 2] = c.z; h1[q * 4 + 3] = c.w;
            }
#pragma unroll
            for (int k = 0; k < 16; k++) {
                float xv = x[k];
#pragma unroll
                for (int o = 0; o < 64; o++) h1[o] = fmaf(xv, Ws1[k * 64 + o], h1[o]);
            }
#pragma unroll
            for (int o = 0; o < 64; o++) h1[o] = silu(h1[o]);

            float e = bs3[0] + shift[spi];
#pragma unroll
            for (int cbk = 0; cbk < 4; cbk++) {
                float h2[16];
#pragma unroll
                for (int o = 0; o < 16; o++) h2[o] = bs2[cbk * 16 + o];
#pragma unroll
                for (int k = 0; k < 64; k++) {
                    float xv = h1[k];
#pragma unroll
                    for (int o = 0; o < 16; o++)
                        h2[o] = fmaf(xv, Ws2[k * 64 + cbk * 16 + o], h2[o]);
                }
#pragma unroll
                for (int o = 0; o < 16; o++)
                    e = fmaf(silu(h2[o]), Ws3[cbk * 16 + o], e);
            }
            e_acc = e;
        } else {
            // ---- magnetic head y ----
            int h = y;
            int kk = (h <= 5) ? h : (h - 1);
            const float4* pk_ = (const float4*)(segbuf + kk * PLANE + a * 8);
            float4 s0 = pk_[0], s1 = pk_[1];
            float amp = (h == 0 || h == 5) ? packed[a * 8 + 6] : 1.f;
            float x[8] = {s0.x * amp, s0.y * amp, s0.z * amp, s0.w * amp,
                          s1.x * amp, s1.y * amp, s1.z * amp, s1.w * amp};

            float hm1[32];
            const float4* cb4 = (const float4*)(c1m + (h * 4 + spi) * 32);
#pragma unroll
            for (int q = 0; q < 8; q++) {
                float4 c = cb4[q];
                hm1[q * 4 + 0] = c.x; hm1[q * 4 + 1] = c.y;
                hm1[q * 4 + 2] = c.z; hm1[q * 4 + 3] = c.w;
            }
            const float* wb1 = Wm1 + h * 768;
#pragma unroll
            for (int d = 0; d < 8; d++) {
                float xv = x[d];
#pragma unroll
                for (int o = 0; o < 32; o++) hm1[o] = fmaf(xv, wb1[d * 32 + o], hm1[o]);
            }
#pragma unroll
            for (int o = 0; o < 32; o++) hm1[o] = silu(hm1[o]);

            const float* wb2 = Wm2 + h * 1024;
            float e = bm3[h];
#pragma unroll
            for (int cbk = 0; cbk < 2; cbk++) {
                float h2[16];
#pragma unroll
                for (int o = 0; o < 16; o++) h2[o] = bm2[h * 32 + cbk * 16 + o];
#pragma unroll
                for (int d = 0; d < 32; d++) {
                    float xv = hm1[d];
#pragma unroll
                    for (int o = 0; o < 16; o++)
                        h2[o] = fmaf(xv, wb2[d * 32 + cbk * 16 + o], h2[o]);
                }
#pragma unroll
                for (int o = 0; o < 16; o++)
                    e = fmaf(silu(h2[o]), Wm3[h * 32 + cbk * 16 + o], e);
            }
            e_acc = e;
        }
        atomicAdd(&spart[batch[a]], e_acc);
    }
    __syncthreads();
    if (t < NSTRUCT) {
        float v = spart[t];
        if (v != 0.f) atomicAdd(&out[t], v);
    }
}

// ---------------- launch ----------------

extern "C" void kernel_launch(void* const* d_in, const int* in_sizes, int n_in,
                              void* d_out, int out_size, void* d_ws, size_t ws_size,
                              hipStream_t stream) {
    const float* pos   = (const float*)d_in[0];
    const float* mmv   = (const float*)d_in[1];
    const int* species = (const int*)d_in[2];
    const int* i_idx   = (const int*)d_in[3];
    const int* j_idx   = (const int*)d_in[4];
    const int* batch   = (const int*)d_in[5];
    const float* cheb  = (const float*)d_in[6];
    const float* embt  = (const float*)d_in[7];
    const float* shift = (const float*)d_in[8];
    const float* Ws1 = (const float*)d_in[9];
    const float* bs1 = (const float*)d_in[10];
    const float* Ws2 = (const float*)d_in[11];
    const float* bs2 = (const float*)d_in[12];
    const float* Ws3 = (const float*)d_in[13];
    const float* bs3 = (const float*)d_in[14];
    const float* Wm1 = (const float*)d_in[15];
    const float* bm1 = (const float*)d_in[16];
    const float* Wm2 = (const float*)d_in[17];
    const float* bm2 = (const float*)d_in[18];
    const float* Wm3 = (const float*)d_in[19];
    const float* bm3 = (const float*)d_in[20];
    float* out = (float*)d_out;

    char* ws = (char*)d_ws;
    int* bucket_cursor = (int*)(ws + 0);          // 6.3 KB (zeroed)
    float* c1m         = (float*)(ws + 8192);     // 4.6 KB
    float* c1s         = (float*)(ws + 16384);    // 1 KB
    float* packed      = (float*)(ws + 20480);    // 3.2 MB
    float* segbuf      = (float*)(ws + 3220480);  // 28.8 MB (9 planes x 3.2 MB)
    unsigned* vb       = (unsigned*)(ws + 32020480); // 9.6 MB (end ~41.6 MB)

    const int NB_ATOM = (N_ATOMS + 255) / 256;     // 391
    const int NB_EPB  = (N_EDGES + EPB - 1) / EPB; // 196

    hipMemsetAsync(bucket_cursor, 0, NBUCK * sizeof(int), stream);
    hipMemsetAsync(out, 0, NSTRUCT * sizeof(float), stream);

    k_pack<<<NB_ATOM, 256, 0, stream>>>(pos, mmv, species, packed,
                                        embt, Wm1, bm1, Ws1, bs1, c1m, c1s);
    k_bscatter<<<NB_EPB, 1024, 0, stream>>>(i_idx, j_idx, bucket_cursor, vb);
    k_fused<<<NBUCK, 256, 0, stream>>>(bucket_cursor, vb, packed, cheb, segbuf);
    dim3 tailGrid(NB_ATOM, 10);
    k_tail<<<tailGrid, 256, 0, stream>>>(segbuf, packed, species, batch, c1s, c1m, shift,
                                         Ws1, Ws2, bs2, Ws3, bs3,
                                         Wm1, Wm2, bm2, Wm3, bm3, out);
}